// Round 10
// baseline (979.606 us; speedup 1.0000x reference)
//
#include <hip/hip_runtime.h>
#include <stdint.h>
#include <stddef.h>

#define NH 32
#define HD 128
#define HID 4096
#define QLEN 2048
#define KBLEN 1024
#define NTOPK 128
#define KVLEN 2176   // NTOPK + QLEN
#define PADV -1e9f
#define SCALE 0.08838834764831845f
#define LOG2E 1.4426950408889634f
#define SC2 (SCALE * LOG2E)          // score scale in log2 domain (folded into Q)
#define DEFER_THR 8.0f

typedef __attribute__((ext_vector_type(4))) float f32x4;
typedef __attribute__((ext_vector_type(4))) unsigned short u16x4;
typedef __attribute__((ext_vector_type(4))) unsigned u32x4;
typedef __attribute__((ext_vector_type(8))) short s16x8;

typedef const __attribute__((address_space(1))) void* gas1_t;
typedef __attribute__((address_space(3))) void* las3_t;

__device__ __forceinline__ void gload_lds16(const void* g, void* l) {
  __builtin_amdgcn_global_load_lds((gas1_t)g, (las3_t)l, 16, 0, 0);
}

__device__ __forceinline__ unsigned short f2bf(float x) {
  union { float f; unsigned u; } z; z.f = x;
  unsigned r = z.u + 0x7fffu + ((z.u >> 16) & 1u);
  return (unsigned short)(r >> 16);
}

// packed f32x2 -> bf16x2 (RNE); lo <- s0, hi <- s1  [T12 recipe, no builtin on gfx950]
__device__ __forceinline__ unsigned cvt_pk_bf16(float s0, float s1) {
  unsigned d;
  asm volatile("v_cvt_pk_bf16_f32 %0, %1, %2" : "=v"(d) : "v"(s0), "v"(s1));
  return d;
}

// ---------------- small prep kernels ----------------

__global__ void k_cast(const float* __restrict__ src, unsigned short* __restrict__ dst, int n4) {
  int i = blockIdx.x * 256 + threadIdx.x;
  if (i >= n4) return;
  f32x4 v = ((const f32x4*)src)[i];
  u16x4 o;
  o[0] = f2bf(v[0]); o[1] = f2bf(v[1]); o[2] = f2bf(v[2]); o[3] = f2bf(v[3]);
  ((u16x4*)dst)[i] = o;
}

// column sums of hidden: two-stage, deterministic (no atomics -> top-k stable)
__global__ void k_rowsum_p(const float* __restrict__ x, float* __restrict__ part) {
  int d = blockIdx.x * 256 + threadIdx.x;
  int q0 = blockIdx.y * 128;
  float acc = 0.f;
  for (int q = q0; q < q0 + 128; ++q) acc += x[(size_t)q * HID + d];
  part[(size_t)blockIdx.y * HID + d] = acc;
}
__global__ void k_rowsum_r(const float* __restrict__ part, float* __restrict__ out) {
  int d = blockIdx.x * 256 + threadIdx.x;
  float acc = 0.f;
#pragma unroll
  for (int i = 0; i < 16; ++i) acc += part[(size_t)i * HID + d];
  out[d] = acc;
}

// out[n] = s * dot(vec, mat[n,:]) ; one wave per n, 4 waves/block
__global__ void k_dotrows(const float* __restrict__ vec, const float* __restrict__ mat,
                          float* __restrict__ out, int K, float s) {
  int n = blockIdx.x * 4 + (threadIdx.x >> 6);
  int lane = threadIdx.x & 63;
  const float* row = mat + (size_t)n * K;
  float acc = 0.f;
  for (int j = lane; j < K; j += 64) acc += vec[j] * row[j];
#pragma unroll
  for (int off = 32; off > 0; off >>= 1) acc += __shfl_down(acc, off, 64);
  if (lane == 0) out[n] = acc * s;
}

// stable top-k by rank counting (tie-break: lower index wins, matches lax.top_k)
__global__ void k_topk(const float* __restrict__ scores, int* __restrict__ idx) {
  __shared__ float s[KBLEN];
  int t = threadIdx.x;
  s[t] = scores[t];
  __syncthreads();
  float mine = s[t];
  int rank = 0;
  for (int j = 0; j < KBLEN; ++j) {
    float v = s[j];
    rank += (v > mine) || (v == mine && j < t);
  }
  if (rank < NTOPK) idx[rank] = t;
}

// cos/sin table, interleaved pairs: cs[p*64+i] = {cos, sin} of pos_p * invf_i
__global__ void k_cs(const int* __restrict__ pos_ids, float2* __restrict__ cs) {
  int t = blockIdx.x * 256 + threadIdx.x;   // QLEN*64 threads
  int p = t >> 6, i = t & 63;
  float pos = (float)pos_ids[p];
  float invf = powf(10000.0f, -(float)i / 64.0f);
  float a = pos * invf;
  cs[p * 64 + i] = make_float2(cosf(a), sinf(a));
}

// gather selected KB rows: K -> kall[h][i][d], V -> vallT[h][d][i] (transposed)
__global__ void k_gather(const float* __restrict__ kbk, const float* __restrict__ kbv,
                         const int* __restrict__ idx,
                         unsigned short* __restrict__ kall, unsigned short* __restrict__ vallT) {
  int t = blockIdx.x * 256 + threadIdx.x;   // NH*NTOPK*HD threads
  int d = t & 127;
  int i = (t >> 7) & 127;
  int hh = t >> 14;
  int kr = idx[i];
  size_t src = (size_t)kr * HID + hh * HD + d;
  kall[((size_t)hh * KVLEN + i) * HD + d] = f2bf(kbk[src]);
  vallT[((size_t)hh * HD + d) * KVLEN + i] = f2bf(kbv[src]);
}

// ---------------- bf16 MFMA GEMM: C[m,n] = sum_k A[m,k]*B[n,k] ----------------
// A: bf16 (global_load_lds staging). B: fp32 weights, REG-STAGED with in-flight
// fp32->bf16 conversion (v_cvt_pk_bf16_f32) -- eliminates the separate weight
// cast pass (100MB traffic / weight). 3 LDS buffers, one barrier per K-tile.
// Schedule per tile kt: ph0: stageA(kt+2) + writeB(kt+1) c01 | ph1: writeB c23
// | ph2: loadB(kt+2) regs. cvt's compiler vmcnt wait lands at vmcnt(2)
// (B(kt+1) was the last vmem of tile kt-1; only A(kt+2) issued after), so
// A-prefetch stays in flight (T4 preserved).
// MODE 0: fp32 row-major Cf. MODE 2: RoPE-fused bf16 head layout (qsc scale).
// MODE 3: transposed bf16 Cb[h][d][RO+m] direct stores. MODE 1: bf16 head layout.
#define GBK 64
#define ABUF 8192    // elems per buffer for A (128x64)
#define BBUF 16384   // elems per buffer for B (256x64)
#define BUFE (ABUF + BBUF)

template<int MODE>
__global__ __launch_bounds__(512)
void gemm_bt(const unsigned short* __restrict__ A, const float* __restrict__ B,
             float* __restrict__ Cf, unsigned short* __restrict__ Cb,
             int M, int N, int K, int RH, int RO, const float2* __restrict__ cs2,
             float qsc) {
  __shared__ unsigned short lds[3 * BUFE];   // 144 KiB
  const int tid = threadIdx.x;
  const int lane = tid & 63;
  const int wave = tid >> 6;
  const int lo = lane & 15, hi = lane >> 4;
  const int wm = wave >> 2, wn = wave & 3;

  // T1: bijective XCD swizzle (nwg % 8 == 0 by construction: 256 blocks)
  const int nwg = gridDim.x * gridDim.y;
  const int orig = blockIdx.y * gridDim.x + blockIdx.x;
  const int wg = (orig & 7) * (nwg >> 3) + (orig >> 3);
  const int bx = wg % gridDim.x, by = wg / gridDim.x;
  const int m0 = by * 128, n0 = bx * 256;

  auto stageA = [&](int kt, int bufe, int g) {
    int j0 = g * 512 + wave * 64;
    int j = j0 + lane;
    int row = j >> 3, cb = j & 7;
    gload_lds16(A + (size_t)(m0 + row) * K + kt * GBK + ((cb ^ (row & 7)) << 3),
                (void*)(lds + bufe + j0 * 8));
  };

  // B reg staging: thread t owns chunks j = t*4 .. t*4+3 (chunk = 8 bf16 = (row,cb))
  f32x4 breg[8];
  auto loadB = [&](int kt) {
#pragma unroll
    for (int c = 0; c < 4; ++c) {
      int j = tid * 4 + c;
      int row = j >> 3, cb = j & 7;
      const float* src = B + (size_t)(n0 + row) * K + kt * GBK + ((cb ^ (row & 7)) << 3);
      breg[c * 2]     = *(const f32x4*)(src);
      breg[c * 2 + 1] = *(const f32x4*)(src + 4);
    }
  };
  auto writeB = [&](int bufe, int c) {   // one chunk: cvt 8 f32 -> 8 bf16, 1 b128 write
    int j = tid * 4 + c;
    u32x4 u;
    f32x4 v0 = breg[c * 2], v1 = breg[c * 2 + 1];
    u[0] = cvt_pk_bf16(v0[0], v0[1]);
    u[1] = cvt_pk_bf16(v0[2], v0[3]);
    u[2] = cvt_pk_bf16(v1[0], v1[1]);
    u[3] = cvt_pk_bf16(v1[2], v1[3]);
    *(u32x4*)(lds + bufe + ABUF + j * 8) = u;
  };

  f32x4 acc[4][4] = {};

  // ---- prologue: tile0 B via regs (serial), tile0/1 A in flight, tile1 B held
  loadB(0);
  stageA(0, 0, 0); stageA(0, 0, 1);
  asm volatile("s_waitcnt vmcnt(2)" ::: "memory");   // B(0) regs ready; A(0) may fly
#pragma unroll
  for (int c = 0; c < 4; ++c) writeB(0, c);
  stageA(1, BUFE, 0); stageA(1, BUFE, 1);
  loadB(1);                                          // held into tile 0
  asm volatile("s_waitcnt lgkmcnt(0)" ::: "memory"); // ds_writes of B(0) done

  const int NT = K / GBK;
  const int sa = (lo & 7) << 3;      // read-side swizzle (elems)
  // column-group base: head-pair-local mapping {0,16,64,80}
  const int bbase = (wn >> 1) * 128 + (wn & 1) * 32;
  int bi = 0;

  for (int kt = 0; kt < NT; ++kt) {
    asm volatile("s_waitcnt vmcnt(10)" ::: "memory");  // A(kt) done (cvt-waits subsume)
    __builtin_amdgcn_sched_barrier(0);
    __builtin_amdgcn_s_barrier();
    __builtin_amdgcn_sched_barrier(0);

    const int bufe = bi * BUFE;
    const int nbufe  = ((bi + 2 >= 3) ? bi - 1 : bi + 2) * BUFE;   // buf(kt+2)
    const int wbufe  = ((bi + 1 >= 3) ? bi - 2 : bi + 1) * BUFE;   // buf(kt+1)
    const bool pre = (kt + 2 < NT);
    const bool wnext = (kt + 1 < NT);
    const unsigned short* Ab = lds + bufe;
    const unsigned short* Bb = lds + bufe + ABUF;
    const int arow = wm * 64 + lo;
    const int brow = bbase + lo;

    s16x8 af[4], b01[2], b23[2];
    const int c0 = (hi * 8) ^ sa;          // kk=0 swizzled col
    const int c1 = (32 + hi * 8) ^ sa;     // kk=1 swizzled col

    // ---- phase 0: frag A(kk0)+B01(kk0) | stageA(kt+2) | writeB(kt+1) c0,c1 | MFMA
#pragma unroll
    for (int i = 0; i < 4; ++i) af[i] = *(const s16x8*)(Ab + (arow + i * 16) * 64 + c0);
    b01[0] = *(const s16x8*)(Bb + (brow +  0) * 64 + c0);
    b01[1] = *(const s16x8*)(Bb + (brow + 16) * 64 + c0);
    if (pre) { stageA(kt + 2, nbufe, 0); stageA(kt + 2, nbufe, 1); }
    if (wnext) { writeB(wbufe, 0); writeB(wbufe, 1); }
    asm volatile("s_waitcnt lgkmcnt(0)" ::: "memory");
    __builtin_amdgcn_sched_barrier(0);
    __builtin_amdgcn_s_setprio(1);
#pragma unroll
    for (int i = 0; i < 4; ++i) {
      acc[i][0] = __builtin_amdgcn_mfma_f32_16x16x32_bf16(af[i], b01[0], acc[i][0], 0, 0, 0);
      acc[i][1] = __builtin_amdgcn_mfma_f32_16x16x32_bf16(af[i], b01[1], acc[i][1], 0, 0, 0);
    }
    __builtin_amdgcn_s_setprio(0);

    // ---- phase 1: frag B23(kk0) | writeB(kt+1) c2,c3 | MFMA
    b23[0] = *(const s16x8*)(Bb + (brow + 64) * 64 + c0);
    b23[1] = *(const s16x8*)(Bb + (brow + 80) * 64 + c0);
    if (wnext) { writeB(wbufe, 2); writeB(wbufe, 3); }
    asm volatile("s_waitcnt lgkmcnt(0)" ::: "memory");
    __builtin_amdgcn_sched_barrier(0);
    __builtin_amdgcn_s_setprio(1);
#pragma unroll
    for (int i = 0; i < 4; ++i) {
      acc[i][2] = __builtin_amdgcn_mfma_f32_16x16x32_bf16(af[i], b23[0], acc[i][2], 0, 0, 0);
      acc[i][3] = __builtin_amdgcn_mfma_f32_16x16x32_bf16(af[i], b23[1], acc[i][3], 0, 0, 0);
    }
    __builtin_amdgcn_s_setprio(0);

    // ---- phase 2: frag A(kk1)+B01(kk1) | loadB(kt+2) regs | MFMA
#pragma unroll
    for (int i = 0; i < 4; ++i) af[i] = *(const s16x8*)(Ab + (arow + i * 16) * 64 + c1);
    b01[0] = *(const s16x8*)(Bb + (brow +  0) * 64 + c1);
    b01[1] = *(const s16x8*)(Bb + (brow + 16) * 64 + c1);
    if (pre) loadB(kt + 2);
    asm volatile("s_waitcnt lgkmcnt(0)" ::: "memory");
    __builtin_amdgcn_sched_barrier(0);
    __builtin_amdgcn_s_setprio(1);
#pragma unroll
    for (int i = 0; i < 4; ++i) {
      acc[i][0] = __builtin_amdgcn_mfma_f32_16x16x32_bf16(af[i], b01[0], acc[i][0], 0, 0, 0);
      acc[i][1] = __builtin_amdgcn_mfma_f32_16x16x32_bf16(af[i], b01[1], acc[i][1], 0, 0, 0);
    }
    __builtin_amdgcn_s_setprio(0);

    // ---- phase 3: frag B23(kk1) | MFMA
    b23[0] = *(const s16x8*)(Bb + (brow + 64) * 64 + c1);
    b23[1] = *(const s16x8*)(Bb + (brow + 80) * 64 + c1);
    asm volatile("s_waitcnt lgkmcnt(0)" ::: "memory");
    __builtin_amdgcn_sched_barrier(0);
    __builtin_amdgcn_s_setprio(1);
#pragma unroll
    for (int i = 0; i < 4; ++i) {
      acc[i][2] = __builtin_amdgcn_mfma_f32_16x16x32_bf16(af[i], b23[0], acc[i][2], 0, 0, 0);
      acc[i][3] = __builtin_amdgcn_mfma_f32_16x16x32_bf16(af[i], b23[1], acc[i][3], 0, 0, 0);
    }
    __builtin_amdgcn_s_setprio(0);

    bi = (bi + 1 == 3) ? 0 : bi + 1;
  }

  // epilogue: col = n0 + bbase + (j>>1)*64 + (j&1)*16 + lo   [remapped groups]
  if (MODE == 2) {
    // RoPE: pair (acc[i][j], acc[i][j+2]) = (x[d], x[d+64]), d < 64; scaled by qsc
#pragma unroll
    for (int i = 0; i < 4; ++i) {
#pragma unroll
      for (int j = 0; j < 2; ++j) {
#pragma unroll
        for (int r = 0; r < 4; ++r) {
          int row = m0 + wm * 64 + i * 16 + hi * 4 + r;
          int col = n0 + bbase + j * 16 + lo;
          int hh = col >> 7, d = col & 127;          // d in [0,64)
          float2 cp = cs2[row * 64 + d];
          float x1 = acc[i][j][r] * qsc, x2 = acc[i][j + 2][r] * qsc;
          size_t base = ((size_t)hh * RH + RO + row) * HD;
          Cb[base + d]      = f2bf(x1 * cp.x - x2 * cp.y);
          Cb[base + d + 64] = f2bf(x2 * cp.x + x1 * cp.y);
        }
      }
    }
  } else if (MODE == 3) {
    // transposed store: Cb[h][d][RO + kv], 4 consecutive kv per reg quad
#pragma unroll
    for (int i = 0; i < 4; ++i) {
#pragma unroll
      for (int j = 0; j < 4; ++j) {
        int rowb = m0 + wm * 64 + i * 16 + hi * 4;
        int col = n0 + bbase + (j >> 1) * 64 + (j & 1) * 16 + lo;
        int hh = col >> 7, d = col & 127;
        u16x4 o4;
#pragma unroll
        for (int r = 0; r < 4; ++r) o4[r] = f2bf(acc[i][j][r]);
        *(u16x4*)(Cb + ((size_t)hh * HD + d) * RH + RO + rowb) = o4;
      }
    }
  } else {
#pragma unroll
    for (int i = 0; i < 4; ++i) {
#pragma unroll
      for (int j = 0; j < 4; ++j) {
#pragma unroll
        for (int r = 0; r < 4; ++r) {
          int row = m0 + wm * 64 + i * 16 + hi * 4 + r;   // C/D: row=(l>>4)*4+reg
          int col = n0 + bbase + (j >> 1) * 64 + (j & 1) * 16 + lo;
          float v = acc[i][j][r];
          if (MODE == 0) {
            Cf[(size_t)row * N + col] = v;
          } else {
            int hh = col >> 7, d = col & 127;
            Cb[((size_t)hh * RH + RO + row) * HD + d] = f2bf(v);
          }
        }
      }
    }
  }
}

// ---------------- flash attention (exact R7 structure: best measured) ----------------
__global__ __launch_bounds__(256)
void attn_kernel(const unsigned short* __restrict__ qh,
                 const unsigned short* __restrict__ kall,
                 const unsigned short* __restrict__ vallT,
                 const float* __restrict__ sshift,
                 unsigned short* __restrict__ ctx) {
  __shared__ __align__(1024) unsigned short Ks[64 * 128];
  __shared__ __align__(1024) unsigned short Vs[128 * 64];
  __shared__ __align__(16)  unsigned short Plds[4][16 * 72];

  int orig = blockIdx.y * 32 + blockIdx.x;
  int wgid = (orig & 7) * 128 + (orig >> 3);   // bijective XCD swizzle (1024 = 8*128)
  int h = wgid >> 5;
  int qc = 31 - (wgid & 31);                   // heaviest chunks launch first

  const int tid = threadIdx.x;
  const int lane = tid & 63;
  const int wave = tid >> 6;
  const int lo = lane & 15;
  const int hi = lane >> 4;
  const float shiftL = sshift[h] * LOG2E;

  const unsigned short* kb = kall + (size_t)h * KVLEN * HD;
  const unsigned short* vtb = vallT + (size_t)h * HD * KVLEN;

  const int m0 = qc * 64;
  const int nt = qc + 3;
  const int qrow = m0 + wave * 16 + hi * 4;

  s16x8 qf[4];
  {
    const unsigned short* qp = qh + ((size_t)h * QLEN + m0 + wave * 16 + lo) * HD + hi * 8;
#pragma unroll
    for (int kc = 0; kc < 4; ++kc) qf[kc] = *(const s16x8*)(qp + kc * 32);
  }

  float m_run[4], l_part[4];
#pragma unroll
  for (int r = 0; r < 4; ++r) { m_run[r] = -1e30f; l_part[r] = 0.f; }
  f32x4 o[8] = {};

  for (int kt = 0; kt < nt; ++kt) {
    const unsigned short* kg = kb + (size_t)kt * 64 * HD;
    const unsigned short* vg = vtb + kt * 64;
    __syncthreads();   // prior tile's readers done before overwrite
#pragma unroll
    for (int it = 0; it < 4; ++it) {
      int j0 = it * 256 + wave * 64;
      int j = j0 + lane;
      int row = j >> 4, cb = j & 15;
      gload_lds16(kg + row * 128 + ((cb ^ (row & 7)) * 8), (void*)(Ks + j0 * 8));
      int d = j >> 3, c = j & 7;
      gload_lds16(vg + (size_t)d * KVLEN + ((c ^ (d & 7)) << 3), (void*)(Vs + j0 * 8));
    }
    __syncthreads();   // implicit vmcnt(0): tile staged & visible

    // S = Q K^T : 16 q-rows x 64 keys per wave (Q pre-scaled by SC2)
    f32x4 s[4] = {};
#pragma unroll
    for (int kc = 0; kc < 4; ++kc) {
#pragma unroll
      for (int g = 0; g < 4; ++g) {
        int key = g * 16 + lo;
        s16x8 kf = *(const s16x8*)(Ks + key * 128 + (((kc * 4 + hi) ^ (key & 7)) * 8));
        s[g] = __builtin_amdgcn_mfma_f32_16x16x32_bf16(qf[kc], kf, s[g], 0, 0, 0);
      }
    }

    // tile-type adjustment (uniform branches)
    if (kt < 2) {
#pragma unroll
      for (int g = 0; g < 4; ++g)
#pragma unroll
        for (int r = 0; r < 4; ++r) s[g][r] += shiftL;
    } else if (kt == nt - 1) {
      const int kvbase = kt * 64;
#pragma unroll
      for (int r = 0; r < 4; ++r) {
        int qr = qrow + r;
#pragma unroll
        for (int g = 0; g < 4; ++g) {
          int kv = kvbase + g * 16 + lo;
          s[g][r] = (kv - NTOPK > qr) ? PADV : s[g][r];
        }
      }
    }

    // vote-based defer-max
    float mx[4];
    bool need = false;
#pragma unroll
    for (int r = 0; r < 4; ++r) {
      mx[r] = fmaxf(fmaxf(s[0][r], s[1][r]), fmaxf(s[2][r], s[3][r]));
      need = need || (mx[r] > m_run[r] + DEFER_THR);
    }
    if (__any((int)need)) {
#pragma unroll
      for (int off = 1; off < 16; off <<= 1)
#pragma unroll
        for (int r = 0; r < 4; ++r) mx[r] = fmaxf(mx[r], __shfl_xor(mx[r], off, 64));
#pragma unroll
      for (int r = 0; r < 4; ++r) {
        float mn = fmaxf(m_run[r], mx[r]);
        float alpha = __builtin_amdgcn_exp2f(m_run[r] - mn);
        m_run[r] = mn;
        l_part[r] *= alpha;
#pragma unroll
        for (int db = 0; db < 8; ++db) o[db][r] *= alpha;
      }
    }

    // p = exp2(s - m), lane-partial l, P -> LDS
#pragma unroll
    for (int r = 0; r < 4; ++r) {
#pragma unroll
      for (int g = 0; g < 4; ++g) {
        float p = __builtin_amdgcn_exp2f(s[g][r] - m_run[r]);
        l_part[r] += p;
        Plds[wave][(hi * 4 + r) * 72 + g * 16 + lo] = f2bf(p);
      }
    }

    // PV: A = P (same-wave LDS round trip), B = V^T single b128 per frag
    s16x8 pf0 = *(const s16x8*)(&Plds[wave][lo * 72 + hi * 8]);
    s16x8 pf1 = *(const s16x8*)(&Plds[wave][lo * 72 + 32 + hi * 8]);
#pragma unroll
    for (int db = 0; db < 8; ++db) {
      int d = db * 16 + lo;
      s16x8 vf0 = *(const s16x8*)(Vs + d * 64 + ((hi       ^ (d & 7)) << 3));
      s16x8 vf1 = *(const s16x8*)(Vs + d * 64 + (((4 + hi) ^ (d & 7)) << 3));
      o[db] = __builtin_amdgcn_mfma_f32_16x16x32_bf16(pf0, vf0, o[db], 0, 0, 0);
      o[db] = __builtin_amdgcn_mfma_f32_16x16x32_bf16(pf1, vf1, o[db], 0, 0, 0);
    }
  } // kt

  // reduce lane-partial l across the 16 lo lanes (once per block)
#pragma unroll
  for (int off = 1; off < 16; off <<= 1)
#pragma unroll
    for (int r = 0; r < 4; ++r) l_part[r] += __shfl_xor(l_part[r], off, 64);

  float rinv[4];
#pragma unroll
  for (int r = 0; r < 4; ++r) rinv[r] = __builtin_amdgcn_rcpf(l_part[r]);

  // normalize + write ctx[q][h*128+d] bf16
#pragma unroll
  for (int db = 0; db < 8; ++db) {
#pragma unroll
    for (int r = 0; r < 4; ++r) {
      int row = qrow + r;
      int col = h * HD + db * 16 + lo;
      ctx[(size_t)row * HID + col] = f2bf(o[db][r] * rinv[r]);
    }
  }
}

// ---------------- launch ----------------

extern "C" void kernel_launch(void* const* d_in, const int* in_sizes, int n_in,
                              void* d_out, int out_size, void* d_ws, size_t ws_size,
                              hipStream_t stream) {
  const float* hidden    = (const float*)d_in[0];
  const int*   pos       = (const int*)d_in[2];
  const float* kb_keys   = (const float*)d_in[3];
  const float* kb_values = (const float*)d_in[4];
  const float* Wq        = (const float*)d_in[5];
  const float* Wq2       = (const float*)d_in[6];
  const float* Wk        = (const float*)d_in[7];
  const float* Wv        = (const float*)d_in[8];
  const float* Wo        = (const float*)d_in[9];
  const float* sshift    = (const float*)d_in[10];
  float* out = (float*)d_out;

  char* ws = (char*)d_ws;
  size_t off = 0;
  auto alloc = [&](size_t bytes) { char* p = ws + off; off += (bytes + 255) & ~(size_t)255; return p; };
  unsigned short* hidden_bf = (unsigned short*)alloc((size_t)QLEN * HID * 2);
  unsigned short* qbf       = (unsigned short*)alloc((size_t)NH * QLEN * HD * 2);
  unsigned short* kallp     = (unsigned short*)alloc((size_t)NH * KVLEN * HD * 2);
  unsigned short* vallT     = (unsigned short*)alloc((size_t)NH * HD * KVLEN * 2);
  unsigned short* ctx       = (unsigned short*)alloc((size_t)QLEN * HID * 2);
  float2*         cs2       = (float2*)alloc((size_t)QLEN * 64 * 8);
  float*          part      = (float*)alloc((size_t)16 * HID * 4);
  float*          hsum      = (float*)alloc(HID * 4);
  float*          qs        = (float*)alloc(HID * 4);
  float*          scores    = (float*)alloc(KBLEN * 4);
  int*            idx       = (int*)alloc(NTOPK * 4);

  dim3 blk(256);

  k_cast<<<QLEN * HID / 4 / 256, blk, 0, stream>>>(hidden, hidden_bf, QLEN * HID / 4);
  k_rowsum_p<<<dim3(HID / 256, 16), blk, 0, stream>>>(hidden, part);
  k_rowsum_r<<<HID / 256, blk, 0, stream>>>(part, hsum);
  k_dotrows<<<HID / 4, blk, 0, stream>>>(hsum, Wq2, qs, HID, 1.0f);
  k_dotrows<<<KBLEN / 4, blk, 0, stream>>>(qs, kb_keys, scores, HID, SCALE);
  k_topk<<<1, KBLEN, 0, stream>>>(scores, idx);
  k_cs<<<QLEN * 64 / 256, blk, 0, stream>>>(pos, cs2);

  dim3 ggrid(HID / 256, QLEN / 128);  // (16, 16) = 256 blocks, 1/CU
  dim3 gblk(512);

  // Q projection + RoPE (pre-scaled by SC2) -> qbf[h][q][d]   [B = fp32 Wq, fused cast]
  gemm_bt<2><<<ggrid, gblk, 0, stream>>>(hidden_bf, Wq, nullptr, qbf, QLEN, HID, HID, QLEN, 0, cs2, (float)SC2);
  // K projection + RoPE -> k_all[h][128+q][d]
  gemm_bt<2><<<ggrid, gblk, 0, stream>>>(hidden_bf, Wk, nullptr, kallp, QLEN, HID, HID, KVLEN, NTOPK, cs2, 1.0f);
  // V projection -> v_all^T[h][d][128+q]
  gemm_bt<3><<<ggrid, gblk, 0, stream>>>(hidden_bf, Wv, nullptr, vallT, QLEN, HID, HID, KVLEN, NTOPK, cs2, 1.0f);

  // gather selected KB keys/values into k_all[:, :128] / v_all^T[:, :, :128]
  k_gather<<<NH * NTOPK * HD / 256, blk, 0, stream>>>(kb_keys, kb_values, idx, kallp, vallT);

  // flash attention -> ctx bf16 [q][h*128+d]
  dim3 agrid(32, NH);   // 1024 single-chunk blocks
  attn_kernel<<<agrid, blk, 0, stream>>>(qbf, kallp, vallT, sshift, ctx);

  // output projection -> d_out fp32
  gemm_bt<0><<<ggrid, gblk, 0, stream>>>(ctx, Wo, out, nullptr, QLEN, HID, HID, 0, 0, cs2, 1.0f);
}

// Round 12
// 737.744 us; speedup vs baseline: 1.3278x; 1.3278x over previous
//
#include <hip/hip_runtime.h>
#include <stdint.h>
#include <stddef.h>

#define NH 32
#define HD 128
#define HID 4096
#define QLEN 2048
#define KBLEN 1024
#define NTOPK 128
#define KVLEN 2176   // NTOPK + QLEN
#define PADV -1e9f
#define SCALE 0.08838834764831845f
#define LOG2E 1.4426950408889634f
#define SC2 (SCALE * LOG2E)          // score scale in log2 domain (folded into Q)
#define DEFER_THR 8.0f

typedef __attribute__((ext_vector_type(4))) float f32x4;
typedef __attribute__((ext_vector_type(4))) unsigned short u16x4;
typedef __attribute__((ext_vector_type(4))) unsigned u32x4;
typedef __attribute__((ext_vector_type(8))) short s16x8;

typedef const __attribute__((address_space(1))) void* gas1_t;
typedef __attribute__((address_space(3))) void* las3_t;

__device__ __forceinline__ void gload_lds16(const void* g, void* l) {
  __builtin_amdgcn_global_load_lds((gas1_t)g, (las3_t)l, 16, 0, 0);
}

__device__ __forceinline__ unsigned short f2bf(float x) {
  union { float f; unsigned u; } z; z.f = x;
  unsigned r = z.u + 0x7fffu + ((z.u >> 16) & 1u);
  return (unsigned short)(r >> 16);
}

// packed f32x2 -> bf16x2 (RNE); lo <- s0, hi <- s1
__device__ __forceinline__ unsigned cvt_pk_bf16(float s0, float s1) {
  unsigned d;
  asm volatile("v_cvt_pk_bf16_f32 %0, %1, %2" : "=v"(d) : "v"(s0), "v"(s1));
  return d;
}

// ---------------- small prep kernels ----------------

__global__ void k_cast(const float* __restrict__ src, unsigned short* __restrict__ dst, int n4) {
  int i = blockIdx.x * 256 + threadIdx.x;
  if (i >= n4) return;
  f32x4 v = ((const f32x4*)src)[i];
  u16x4 o;
  o[0] = f2bf(v[0]); o[1] = f2bf(v[1]); o[2] = f2bf(v[2]); o[3] = f2bf(v[3]);
  ((u16x4*)dst)[i] = o;
}

// column sums of hidden: two-stage, deterministic (no atomics -> top-k stable)
__global__ void k_rowsum_p(const float* __restrict__ x, float* __restrict__ part) {
  int d = blockIdx.x * 256 + threadIdx.x;
  int q0 = blockIdx.y * 128;
  float acc = 0.f;
  for (int q = q0; q < q0 + 128; ++q) acc += x[(size_t)q * HID + d];
  part[(size_t)blockIdx.y * HID + d] = acc;
}
__global__ void k_rowsum_r(const float* __restrict__ part, float* __restrict__ out) {
  int d = blockIdx.x * 256 + threadIdx.x;
  float acc = 0.f;
#pragma unroll
  for (int i = 0; i < 16; ++i) acc += part[(size_t)i * HID + d];
  out[d] = acc;
}

// out[n] = s * dot(vec, mat[n,:]) ; one wave per n, 4 waves/block
__global__ void k_dotrows(const float* __restrict__ vec, const float* __restrict__ mat,
                          float* __restrict__ out, int K, float s) {
  int n = blockIdx.x * 4 + (threadIdx.x >> 6);
  int lane = threadIdx.x & 63;
  const float* row = mat + (size_t)n * K;
  float acc = 0.f;
  for (int j = lane; j < K; j += 64) acc += vec[j] * row[j];
#pragma unroll
  for (int off = 32; off > 0; off >>= 1) acc += __shfl_down(acc, off, 64);
  if (lane == 0) out[n] = acc * s;
}

// stable top-k by rank counting (tie-break: lower index wins, matches lax.top_k)
__global__ void k_topk(const float* __restrict__ scores, int* __restrict__ idx) {
  __shared__ float s[KBLEN];
  int t = threadIdx.x;
  s[t] = scores[t];
  __syncthreads();
  float mine = s[t];
  int rank = 0;
  for (int j = 0; j < KBLEN; ++j) {
    float v = s[j];
    rank += (v > mine) || (v == mine && j < t);
  }
  if (rank < NTOPK) idx[rank] = t;
}

// cos/sin table, interleaved pairs: cs[p*64+i] = {cos, sin} of pos_p * invf_i
__global__ void k_cs(const int* __restrict__ pos_ids, float2* __restrict__ cs) {
  int t = blockIdx.x * 256 + threadIdx.x;   // QLEN*64 threads
  int p = t >> 6, i = t & 63;
  float pos = (float)pos_ids[p];
  float invf = powf(10000.0f, -(float)i / 64.0f);
  float a = pos * invf;
  cs[p * 64 + i] = make_float2(cosf(a), sinf(a));
}

// gather selected KB rows: K -> kall[h][i][d], V -> vallT[h][d][i] (transposed)
__global__ void k_gather(const float* __restrict__ kbk, const float* __restrict__ kbv,
                         const int* __restrict__ idx,
                         unsigned short* __restrict__ kall, unsigned short* __restrict__ vallT) {
  int t = blockIdx.x * 256 + threadIdx.x;   // NH*NTOPK*HD threads
  int d = t & 127;
  int i = (t >> 7) & 127;
  int hh = t >> 14;
  int kr = idx[i];
  size_t src = (size_t)kr * HID + hh * HD + d;
  kall[((size_t)hh * KVLEN + i) * HD + d] = f2bf(kbk[src]);
  vallT[((size_t)hh * HD + d) * KVLEN + i] = f2bf(kbv[src]);
}

// ---------------- bf16 MFMA GEMM: C[m,n] = sum_k A[m,k]*B[n,k] ----------------
// A: bf16 (global_load_lds staging). B: fp32 weights, REG-STAGED with in-flight
// fp32->bf16 conversion -- eliminates the separate weight cast pass.
// R12 = R10's phase ORDER (writeB(kt+1) BEFORE loadB(kt+2) -- breg consumed
// before clobber; R11 had them swapped = data corruption) + R11's coalesced
// OWNERSHIP u = c*512+tid (consecutive lanes: consecutive 32B global runs,
// consecutive 16B ds_writes; R10's tid*4+c was 2.7x fetch amp + 32-way LDS
// conflicts). ph0 cvt-wait drains to vmcnt(2), keeping stageA(kt+2) in flight.
// MODE 0: fp32 row-major Cf. MODE 2: RoPE-fused bf16 head layout (qsc scale).
// MODE 3: transposed bf16 Cb[h][d][RO+m]. MODE 1: bf16 head layout.
#define GBK 64
#define ABUF 8192    // elems per buffer for A (128x64)
#define BBUF 16384   // elems per buffer for B (256x64)
#define BUFE (ABUF + BBUF)

template<int MODE>
__global__ __launch_bounds__(512)
void gemm_bt(const unsigned short* __restrict__ A, const float* __restrict__ B,
             float* __restrict__ Cf, unsigned short* __restrict__ Cb,
             int M, int N, int K, int RH, int RO, const float2* __restrict__ cs2,
             float qsc) {
  __shared__ unsigned short lds[3 * BUFE];   // 144 KiB
  const int tid = threadIdx.x;
  const int lane = tid & 63;
  const int wave = tid >> 6;
  const int lo = lane & 15, hi = lane >> 4;
  const int wm = wave >> 2, wn = wave & 3;

  // T1: bijective XCD swizzle (nwg % 8 == 0 by construction: 256 blocks)
  const int nwg = gridDim.x * gridDim.y;
  const int orig = blockIdx.y * gridDim.x + blockIdx.x;
  const int wg = (orig & 7) * (nwg >> 3) + (orig >> 3);
  const int bx = wg % gridDim.x, by = wg / gridDim.x;
  const int m0 = by * 128, n0 = bx * 256;

  auto stageA = [&](int kt, int bufe, int g) {
    int j0 = g * 512 + wave * 64;
    int j = j0 + lane;
    int row = j >> 3, cb = j & 7;
    gload_lds16(A + (size_t)(m0 + row) * K + kt * GBK + ((cb ^ (row & 7)) << 3),
                (void*)(lds + bufe + j0 * 8));
  };

  // B reg staging: thread t owns chunks u = c*512 + t (c=0..3); chunk = 8 bf16
  // = 8 fp32 = 32B fp32, loaded as two back-to-back f32x4 (coalesced).
  f32x4 breg[8];
  auto loadB = [&](int kt) {
#pragma unroll
    for (int c = 0; c < 4; ++c) {
      int u = c * 512 + tid;
      int row = u >> 3, cb = u & 7;
      const float* src = B + (size_t)(n0 + row) * K + kt * GBK + ((cb ^ (row & 7)) << 3);
      breg[c * 2]     = *(const f32x4*)(src);
      breg[c * 2 + 1] = *(const f32x4*)(src + 4);
    }
  };
  auto writeB = [&](int bufe, int c) {   // cvt 8 f32 -> 8 bf16, one b128 write
    int u = c * 512 + tid;
    u32x4 uo;
    f32x4 v0 = breg[c * 2], v1 = breg[c * 2 + 1];
    uo[0] = cvt_pk_bf16(v0[0], v0[1]);
    uo[1] = cvt_pk_bf16(v0[2], v0[3]);
    uo[2] = cvt_pk_bf16(v1[0], v1[1]);
    uo[3] = cvt_pk_bf16(v1[2], v1[3]);
    *(u32x4*)(lds + bufe + ABUF + u * 8) = uo;
  };

  f32x4 acc[4][4] = {};

  // ---- prologue: tile0 B via regs (serial), tile0/1 A in flight, tile1 B held
  loadB(0);
  stageA(0, 0, 0); stageA(0, 0, 1);
  asm volatile("s_waitcnt vmcnt(2)" ::: "memory");   // B(0) regs ready; A(0) may fly
#pragma unroll
  for (int c = 0; c < 4; ++c) writeB(0, c);
  stageA(1, BUFE, 0); stageA(1, BUFE, 1);
  loadB(1);                                          // held in breg into tile 0
  asm volatile("s_waitcnt lgkmcnt(0)" ::: "memory"); // ds_writes of B(0) done

  const int NT = K / GBK;
  const int sa = (lo & 7) << 3;      // read-side swizzle (elems)
  // column-group base: head-pair-local mapping {0,16,64,80}
  const int bbase = (wn >> 1) * 128 + (wn & 1) * 32;
  int bi = 0;

  for (int kt = 0; kt < NT; ++kt) {
    asm volatile("s_waitcnt vmcnt(10)" ::: "memory");
    __builtin_amdgcn_sched_barrier(0);
    __builtin_amdgcn_s_barrier();
    __builtin_amdgcn_sched_barrier(0);

    const int bufe = bi * BUFE;
    const int nbufe  = ((bi + 2 >= 3) ? bi - 1 : bi + 2) * BUFE;   // buf(kt+2)
    const int wbufe  = ((bi + 1 >= 3) ? bi - 2 : bi + 1) * BUFE;   // buf(kt+1)
    const bool pre = (kt + 2 < NT);
    const bool wnext = (kt + 1 < NT);
    const unsigned short* Ab = lds + bufe;
    const unsigned short* Bb = lds + bufe + ABUF;
    const int arow = wm * 64 + lo;
    const int brow = bbase + lo;

    s16x8 af[4], b01[2], b23[2];
    const int c0 = (hi * 8) ^ sa;          // kk=0 swizzled col
    const int c1 = (32 + hi * 8) ^ sa;     // kk=1 swizzled col

    // ---- phase 0: frag A(kk0)+B01(kk0) | stageA(kt+2) | writeB(kt+1) c0,c1 | MFMA
#pragma unroll
    for (int i = 0; i < 4; ++i) af[i] = *(const s16x8*)(Ab + (arow + i * 16) * 64 + c0);
    b01[0] = *(const s16x8*)(Bb + (brow +  0) * 64 + c0);
    b01[1] = *(const s16x8*)(Bb + (brow + 16) * 64 + c0);
    if (pre) { stageA(kt + 2, nbufe, 0); stageA(kt + 2, nbufe, 1); }
    if (wnext) { writeB(wbufe, 0); writeB(wbufe, 1); }   // cvt waits loadB(kt+1); stageA(kt+2) stays in flight
    asm volatile("s_waitcnt lgkmcnt(0)" ::: "memory");
    __builtin_amdgcn_sched_barrier(0);
    __builtin_amdgcn_s_setprio(1);
#pragma unroll
    for (int i = 0; i < 4; ++i) {
      acc[i][0] = __builtin_amdgcn_mfma_f32_16x16x32_bf16(af[i], b01[0], acc[i][0], 0, 0, 0);
      acc[i][1] = __builtin_amdgcn_mfma_f32_16x16x32_bf16(af[i], b01[1], acc[i][1], 0, 0, 0);
    }
    __builtin_amdgcn_s_setprio(0);

    // ---- phase 1: frag B23(kk0) | writeB(kt+1) c2,c3 | MFMA j23 kk0
    b23[0] = *(const s16x8*)(Bb + (brow + 64) * 64 + c0);
    b23[1] = *(const s16x8*)(Bb + (brow + 80) * 64 + c0);
    if (wnext) { writeB(wbufe, 2); writeB(wbufe, 3); }
    asm volatile("s_waitcnt lgkmcnt(0)" ::: "memory");
    __builtin_amdgcn_sched_barrier(0);
    __builtin_amdgcn_s_setprio(1);
#pragma unroll
    for (int i = 0; i < 4; ++i) {
      acc[i][2] = __builtin_amdgcn_mfma_f32_16x16x32_bf16(af[i], b23[0], acc[i][2], 0, 0, 0);
      acc[i][3] = __builtin_amdgcn_mfma_f32_16x16x32_bf16(af[i], b23[1], acc[i][3], 0, 0, 0);
    }
    __builtin_amdgcn_s_setprio(0);

    // ---- phase 2: frag A(kk1)+B01(kk1) | loadB(kt+2) regs (breg now free) | MFMA
#pragma unroll
    for (int i = 0; i < 4; ++i) af[i] = *(const s16x8*)(Ab + (arow + i * 16) * 64 + c1);
    b01[0] = *(const s16x8*)(Bb + (brow +  0) * 64 + c1);
    b01[1] = *(const s16x8*)(Bb + (brow + 16) * 64 + c1);
    if (pre) loadB(kt + 2);
    asm volatile("s_waitcnt lgkmcnt(0)" ::: "memory");
    __builtin_amdgcn_sched_barrier(0);
    __builtin_amdgcn_s_setprio(1);
#pragma unroll
    for (int i = 0; i < 4; ++i) {
      acc[i][0] = __builtin_amdgcn_mfma_f32_16x16x32_bf16(af[i], b01[0], acc[i][0], 0, 0, 0);
      acc[i][1] = __builtin_amdgcn_mfma_f32_16x16x32_bf16(af[i], b01[1], acc[i][1], 0, 0, 0);
    }
    __builtin_amdgcn_s_setprio(0);

    // ---- phase 3: frag B23(kk1) | MFMA
    b23[0] = *(const s16x8*)(Bb + (brow + 64) * 64 + c1);
    b23[1] = *(const s16x8*)(Bb + (brow + 80) * 64 + c1);
    asm volatile("s_waitcnt lgkmcnt(0)" ::: "memory");
    __builtin_amdgcn_sched_barrier(0);
    __builtin_amdgcn_s_setprio(1);
#pragma unroll
    for (int i = 0; i < 4; ++i) {
      acc[i][2] = __builtin_amdgcn_mfma_f32_16x16x32_bf16(af[i], b23[0], acc[i][2], 0, 0, 0);
      acc[i][3] = __builtin_amdgcn_mfma_f32_16x16x32_bf16(af[i], b23[1], acc[i][3], 0, 0, 0);
    }
    __builtin_amdgcn_s_setprio(0);

    bi = (bi + 1 == 3) ? 0 : bi + 1;
  }

  // epilogue: col = n0 + bbase + (j>>1)*64 + (j&1)*16 + lo   [remapped groups]
  if (MODE == 2) {
    // RoPE: pair (acc[i][j], acc[i][j+2]) = (x[d], x[d+64]), d < 64; scaled by qsc
#pragma unroll
    for (int i = 0; i < 4; ++i) {
#pragma unroll
      for (int j = 0; j < 2; ++j) {
#pragma unroll
        for (int r = 0; r < 4; ++r) {
          int row = m0 + wm * 64 + i * 16 + hi * 4 + r;
          int col = n0 + bbase + j * 16 + lo;
          int hh = col >> 7, d = col & 127;          // d in [0,64)
          float2 cp = cs2[row * 64 + d];
          float x1 = acc[i][j][r] * qsc, x2 = acc[i][j + 2][r] * qsc;
          size_t base = ((size_t)hh * RH + RO + row) * HD;
          Cb[base + d]      = f2bf(x1 * cp.x - x2 * cp.y);
          Cb[base + d + 64] = f2bf(x2 * cp.x + x1 * cp.y);
        }
      }
    }
  } else if (MODE == 3) {
    // transposed store: Cb[h][d][RO + kv], 4 consecutive kv per reg quad
#pragma unroll
    for (int i = 0; i < 4; ++i) {
#pragma unroll
      for (int j = 0; j < 4; ++j) {
        int rowb = m0 + wm * 64 + i * 16 + hi * 4;
        int col = n0 + bbase + (j >> 1) * 64 + (j & 1) * 16 + lo;
        int hh = col >> 7, d = col & 127;
        u16x4 o4;
#pragma unroll
        for (int r = 0; r < 4; ++r) o4[r] = f2bf(acc[i][j][r]);
        *(u16x4*)(Cb + ((size_t)hh * HD + d) * RH + RO + rowb) = o4;
      }
    }
  } else {
#pragma unroll
    for (int i = 0; i < 4; ++i) {
#pragma unroll
      for (int j = 0; j < 4; ++j) {
#pragma unroll
        for (int r = 0; r < 4; ++r) {
          int row = m0 + wm * 64 + i * 16 + hi * 4 + r;   // C/D: row=(l>>4)*4+reg
          int col = n0 + bbase + (j >> 1) * 64 + (j & 1) * 16 + lo;
          float v = acc[i][j][r];
          if (MODE == 0) {
            Cf[(size_t)row * N + col] = v;
          } else {
            int hh = col >> 7, d = col & 127;
            Cb[((size_t)hh * RH + RO + row) * HD + d] = f2bf(v);
          }
        }
      }
    }
  }
}

// ---------------- flash attention (exact R7 structure: best measured) ----------------
__global__ __launch_bounds__(256)
void attn_kernel(const unsigned short* __restrict__ qh,
                 const unsigned short* __restrict__ kall,
                 const unsigned short* __restrict__ vallT,
                 const float* __restrict__ sshift,
                 unsigned short* __restrict__ ctx) {
  __shared__ __align__(1024) unsigned short Ks[64 * 128];
  __shared__ __align__(1024) unsigned short Vs[128 * 64];
  __shared__ __align__(16)  unsigned short Plds[4][16 * 72];

  int orig = blockIdx.y * 32 + blockIdx.x;
  int wgid = (orig & 7) * 128 + (orig >> 3);   // bijective XCD swizzle (1024 = 8*128)
  int h = wgid >> 5;
  int qc = 31 - (wgid & 31);                   // heaviest chunks launch first

  const int tid = threadIdx.x;
  const int lane = tid & 63;
  const int wave = tid >> 6;
  const int lo = lane & 15;
  const int hi = lane >> 4;
  const float shiftL = sshift[h] * LOG2E;

  const unsigned short* kb = kall + (size_t)h * KVLEN * HD;
  const unsigned short* vtb = vallT + (size_t)h * HD * KVLEN;

  const int m0 = qc * 64;
  const int nt = qc + 3;
  const int qrow = m0 + wave * 16 + hi * 4;

  s16x8 qf[4];
  {
    const unsigned short* qp = qh + ((size_t)h * QLEN + m0 + wave * 16 + lo) * HD + hi * 8;
#pragma unroll
    for (int kc = 0; kc < 4; ++kc) qf[kc] = *(const s16x8*)(qp + kc * 32);
  }

  float m_run[4], l_part[4];
#pragma unroll
  for (int r = 0; r < 4; ++r) { m_run[r] = -1e30f; l_part[r] = 0.f; }
  f32x4 o[8] = {};

  for (int kt = 0; kt < nt; ++kt) {
    const unsigned short* kg = kb + (size_t)kt * 64 * HD;
    const unsigned short* vg = vtb + kt * 64;
    __syncthreads();   // prior tile's readers done before overwrite
#pragma unroll
    for (int it = 0; it < 4; ++it) {
      int j0 = it * 256 + wave * 64;
      int j = j0 + lane;
      int row = j >> 4, cb = j & 15;
      gload_lds16(kg + row * 128 + ((cb ^ (row & 7)) * 8), (void*)(Ks + j0 * 8));
      int d = j >> 3, c = j & 7;
      gload_lds16(vg + (size_t)d * KVLEN + ((c ^ (d & 7)) << 3), (void*)(Vs + j0 * 8));
    }
    __syncthreads();   // implicit vmcnt(0): tile staged & visible

    // S = Q K^T : 16 q-rows x 64 keys per wave (Q pre-scaled by SC2)
    f32x4 s[4] = {};
#pragma unroll
    for (int kc = 0; kc < 4; ++kc) {
#pragma unroll
      for (int g = 0; g < 4; ++g) {
        int key = g * 16 + lo;
        s16x8 kf = *(const s16x8*)(Ks + key * 128 + (((kc * 4 + hi) ^ (key & 7)) * 8));
        s[g] = __builtin_amdgcn_mfma_f32_16x16x32_bf16(qf[kc], kf, s[g], 0, 0, 0);
      }
    }

    // tile-type adjustment (uniform branches)
    if (kt < 2) {
#pragma unroll
      for (int g = 0; g < 4; ++g)
#pragma unroll
        for (int r = 0; r < 4; ++r) s[g][r] += shiftL;
    } else if (kt == nt - 1) {
      const int kvbase = kt * 64;
#pragma unroll
      for (int r = 0; r < 4; ++r) {
        int qr = qrow + r;
#pragma unroll
        for (int g = 0; g < 4; ++g) {
          int kv = kvbase + g * 16 + lo;
          s[g][r] = (kv - NTOPK > qr) ? PADV : s[g][r];
        }
      }
    }

    // vote-based defer-max
    float mx[4];
    bool need = false;
#pragma unroll
    for (int r = 0; r < 4; ++r) {
      mx[r] = fmaxf(fmaxf(s[0][r], s[1][r]), fmaxf(s[2][r], s[3][r]));
      need = need || (mx[r] > m_run[r] + DEFER_THR);
    }
    if (__any((int)need)) {
#pragma unroll
      for (int off = 1; off < 16; off <<= 1)
#pragma unroll
        for (int r = 0; r < 4; ++r) mx[r] = fmaxf(mx[r], __shfl_xor(mx[r], off, 64));
#pragma unroll
      for (int r = 0; r < 4; ++r) {
        float mn = fmaxf(m_run[r], mx[r]);
        float alpha = __builtin_amdgcn_exp2f(m_run[r] - mn);
        m_run[r] = mn;
        l_part[r] *= alpha;
#pragma unroll
        for (int db = 0; db < 8; ++db) o[db][r] *= alpha;
      }
    }

    // p = exp2(s - m), lane-partial l, P -> LDS
#pragma unroll
    for (int r = 0; r < 4; ++r) {
#pragma unroll
      for (int g = 0; g < 4; ++g) {
        float p = __builtin_amdgcn_exp2f(s[g][r] - m_run[r]);
        l_part[r] += p;
        Plds[wave][(hi * 4 + r) * 72 + g * 16 + lo] = f2bf(p);
      }
    }

    // PV: A = P (same-wave LDS round trip), B = V^T single b128 per frag
    s16x8 pf0 = *(const s16x8*)(&Plds[wave][lo * 72 + hi * 8]);
    s16x8 pf1 = *(const s16x8*)(&Plds[wave][lo * 72 + 32 + hi * 8]);
#pragma unroll
    for (int db = 0; db < 8; ++db) {
      int d = db * 16 + lo;
      s16x8 vf0 = *(const s16x8*)(Vs + d * 64 + ((hi       ^ (d & 7)) << 3));
      s16x8 vf1 = *(const s16x8*)(Vs + d * 64 + (((4 + hi) ^ (d & 7)) << 3));
      o[db] = __builtin_amdgcn_mfma_f32_16x16x32_bf16(pf0, vf0, o[db], 0, 0, 0);
      o[db] = __builtin_amdgcn_mfma_f32_16x16x32_bf16(pf1, vf1, o[db], 0, 0, 0);
    }
  } // kt

  // reduce lane-partial l across the 16 lo lanes (once per block)
#pragma unroll
  for (int off = 1; off < 16; off <<= 1)
#pragma unroll
    for (int r = 0; r < 4; ++r) l_part[r] += __shfl_xor(l_part[r], off, 64);

  float rinv[4];
#pragma unroll
  for (int r = 0; r < 4; ++r) rinv[r] = __builtin_amdgcn_rcpf(l_part[r]);

  // normalize + write ctx[q][h*128+d] bf16
#pragma unroll
  for (int db = 0; db < 8; ++db) {
#pragma unroll
    for (int r = 0; r < 4; ++r) {
      int row = qrow + r;
      int col = h * HD + db * 16 + lo;
      ctx[(size_t)row * HID + col] = f2bf(o[db][r] * rinv[r]);
    }
  }
}

// ---------------- launch ----------------

extern "C" void kernel_launch(void* const* d_in, const int* in_sizes, int n_in,
                              void* d_out, int out_size, void* d_ws, size_t ws_size,
                              hipStream_t stream) {
  const float* hidden    = (const float*)d_in[0];
  const int*   pos       = (const int*)d_in[2];
  const float* kb_keys   = (const float*)d_in[3];
  const float* kb_values = (const float*)d_in[4];
  const float* Wq        = (const float*)d_in[5];
  const float* Wq2       = (const float*)d_in[6];
  const float* Wk        = (const float*)d_in[7];
  const float* Wv        = (const float*)d_in[8];
  const float* Wo        = (const float*)d_in[9];
  const float* sshift    = (const float*)d_in[10];
  float* out = (float*)d_out;

  char* ws = (char*)d_ws;
  size_t off = 0;
  auto alloc = [&](size_t bytes) { char* p = ws + off; off += (bytes + 255) & ~(size_t)255; return p; };
  unsigned short* hidden_bf = (unsigned short*)alloc((size_t)QLEN * HID * 2);
  unsigned short* qbf       = (unsigned short*)alloc((size_t)NH * QLEN * HD * 2);
  unsigned short* kallp     = (unsigned short*)alloc((size_t)NH * KVLEN * HD * 2);
  unsigned short* vallT     = (unsigned short*)alloc((size_t)NH * HD * KVLEN * 2);
  unsigned short* ctx       = (unsigned short*)alloc((size_t)QLEN * HID * 2);
  float2*         cs2       = (float2*)alloc((size_t)QLEN * 64 * 8);
  float*          part      = (float*)alloc((size_t)16 * HID * 4);
  float*          hsum      = (float*)alloc(HID * 4);
  float*          qs        = (float*)alloc(HID * 4);
  float*          scores    = (float*)alloc(KBLEN * 4);
  int*            idx       = (int*)alloc(NTOPK * 4);

  dim3 blk(256);

  k_cast<<<QLEN * HID / 4 / 256, blk, 0, stream>>>(hidden, hidden_bf, QLEN * HID / 4);
  k_rowsum_p<<<dim3(HID / 256, 16), blk, 0, stream>>>(hidden, part);
  k_rowsum_r<<<HID / 256, blk, 0, stream>>>(part, hsum);
  k_dotrows<<<HID / 4, blk, 0, stream>>>(hsum, Wq2, qs, HID, 1.0f);
  k_dotrows<<<KBLEN / 4, blk, 0, stream>>>(qs, kb_keys, scores, HID, SCALE);
  k_topk<<<1, KBLEN, 0, stream>>>(scores, idx);
  k_cs<<<QLEN * 64 / 256, blk, 0, stream>>>(pos, cs2);

  dim3 ggrid(HID / 256, QLEN / 128);  // (16, 16) = 256 blocks, 1/CU
  dim3 gblk(512);

  // Q projection + RoPE (pre-scaled by SC2) -> qbf[h][q][d]   [B = fp32 Wq, fused cast]
  gemm_bt<2><<<ggrid, gblk, 0, stream>>>(hidden_bf, Wq, nullptr, qbf, QLEN, HID, HID, QLEN, 0, cs2, (float)SC2);
  // K projection + RoPE -> k_all[h][128+q][d]
  gemm_bt<2><<<ggrid, gblk, 0, stream>>>(hidden_bf, Wk, nullptr, kallp, QLEN, HID, HID, KVLEN, NTOPK, cs2, 1.0f);
  // V projection -> v_all^T[h][d][128+q]
  gemm_bt<3><<<ggrid, gblk, 0, stream>>>(hidden_bf, Wv, nullptr, vallT, QLEN, HID, HID, KVLEN, NTOPK, cs2, 1.0f);

  // gather selected KB keys/values into k_all[:, :128] / v_all^T[:, :, :128]
  k_gather<<<NH * NTOPK * HD / 256, blk, 0, stream>>>(kb_keys, kb_values, idx, kallp, vallT);

  // flash attention -> ctx bf16 [q][h*128+d]
  dim3 agrid(32, NH);   // 1024 single-chunk blocks
  attn_kernel<<<agrid, blk, 0, stream>>>(qbf, kallp, vallT, sshift, ctx);

  // output projection -> d_out fp32
  gemm_bt<0><<<ggrid, gblk, 0, stream>>>(ctx, Wo, out, nullptr, QLEN, HID, HID, 0, 0, cs2, 1.0f);
}

// Round 14
// 565.448 us; speedup vs baseline: 1.7324x; 1.3047x over previous
//
#include <hip/hip_runtime.h>
#include <stdint.h>
#include <stddef.h>

#define NH 32
#define HD 128
#define HID 4096
#define QLEN 2048
#define KBLEN 1024
#define NTOPK 128
#define KVLEN 2176   // NTOPK + QLEN
#define PADV -1e9f
#define SCALE 0.08838834764831845f
#define LOG2E 1.4426950408889634f
#define SC2 (SCALE * LOG2E)          // score scale in log2 domain (folded into Q)
#define DEFER_THR 8.0f

typedef __attribute__((ext_vector_type(4))) float f32x4;
typedef __attribute__((ext_vector_type(4))) unsigned short u16x4;
typedef __attribute__((ext_vector_type(8))) short s16x8;

typedef const __attribute__((address_space(1))) void* gas1_t;
typedef __attribute__((address_space(3))) void* las3_t;

__device__ __forceinline__ void gload_lds16(const void* g, void* l) {
  __builtin_amdgcn_global_load_lds((gas1_t)g, (las3_t)l, 16, 0, 0);
}

__device__ __forceinline__ unsigned short f2bf(float x) {
  union { float f; unsigned u; } z; z.f = x;
  unsigned r = z.u + 0x7fffu + ((z.u >> 16) & 1u);
  return (unsigned short)(r >> 16);
}

// ---------------- small prep kernels ----------------

__global__ void k_cast(const float* __restrict__ src, unsigned short* __restrict__ dst, int n4) {
  int i = blockIdx.x * 256 + threadIdx.x;
  if (i >= n4) return;
  f32x4 v = ((const f32x4*)src)[i];
  u16x4 o;
  o[0] = f2bf(v[0]); o[1] = f2bf(v[1]); o[2] = f2bf(v[2]); o[3] = f2bf(v[3]);
  ((u16x4*)dst)[i] = o;
}

// column sums of hidden: two-stage, deterministic (no atomics -> top-k stable)
__global__ void k_rowsum_p(const float* __restrict__ x, float* __restrict__ part) {
  int d = blockIdx.x * 256 + threadIdx.x;
  int q0 = blockIdx.y * 128;
  float acc = 0.f;
  for (int q = q0; q < q0 + 128; ++q) acc += x[(size_t)q * HID + d];
  part[(size_t)blockIdx.y * HID + d] = acc;
}
__global__ void k_rowsum_r(const float* __restrict__ part, float* __restrict__ out) {
  int d = blockIdx.x * 256 + threadIdx.x;
  float acc = 0.f;
#pragma unroll
  for (int i = 0; i < 16; ++i) acc += part[(size_t)i * HID + d];
  out[d] = acc;
}

// out[n] = s * dot(vec, mat[n,:]) ; one wave per n, 4 waves/block
__global__ void k_dotrows(const float* __restrict__ vec, const float* __restrict__ mat,
                          float* __restrict__ out, int K, float s) {
  int n = blockIdx.x * 4 + (threadIdx.x >> 6);
  int lane = threadIdx.x & 63;
  const float* row = mat + (size_t)n * K;
  float acc = 0.f;
  for (int j = lane; j < K; j += 64) acc += vec[j] * row[j];
#pragma unroll
  for (int off = 32; off > 0; off >>= 1) acc += __shfl_down(acc, off, 64);
  if (lane == 0) out[n] = acc * s;
}

// stable top-k by rank counting (tie-break: lower index wins, matches lax.top_k)
__global__ void k_topk(const float* __restrict__ scores, int* __restrict__ idx) {
  __shared__ float s[KBLEN];
  int t = threadIdx.x;
  s[t] = scores[t];
  __syncthreads();
  float mine = s[t];
  int rank = 0;
  for (int j = 0; j < KBLEN; ++j) {
    float v = s[j];
    rank += (v > mine) || (v == mine && j < t);
  }
  if (rank < NTOPK) idx[rank] = t;
}

// cos/sin table, interleaved pairs: cs[p*64+i] = {cos, sin} of pos_p * invf_i
__global__ void k_cs(const int* __restrict__ pos_ids, float2* __restrict__ cs) {
  int t = blockIdx.x * 256 + threadIdx.x;   // QLEN*64 threads
  int p = t >> 6, i = t & 63;
  float pos = (float)pos_ids[p];
  float invf = powf(10000.0f, -(float)i / 64.0f);
  float a = pos * invf;
  cs[p * 64 + i] = make_float2(cosf(a), sinf(a));
}

// gather selected KB rows: K -> kall[h][i][d], V -> vallT[h][d][i] (transposed)
__global__ void k_gather(const float* __restrict__ kbk, const float* __restrict__ kbv,
                         const int* __restrict__ idx,
                         unsigned short* __restrict__ kall, unsigned short* __restrict__ vallT) {
  int t = blockIdx.x * 256 + threadIdx.x;   // NH*NTOPK*HD threads
  int d = t & 127;
  int i = (t >> 7) & 127;
  int hh = t >> 14;
  int kr = idx[i];
  size_t src = (size_t)kr * HID + hh * HD + d;
  kall[((size_t)hh * KVLEN + i) * HD + d] = f2bf(kbk[src]);
  vallT[((size_t)hh * HD + d) * KVLEN + i] = f2bf(kbv[src]);
}

// ---------------- bf16 MFMA GEMM: C[m,n] = sum_k A[m,k]*B[n,k] ----------------
// Pipelined template (T1+T2+T3+T4+T5): BM=128, BN=256, BK=64, 512 threads =
// 8 waves (2M x 4N), per-wave 64x64 output. 3 LDS buffers, ONE raw s_barrier
// + ONE counted vmcnt(6) per K-tile. Wave's 4 column groups remapped to
// {d, d+16, d+64, d+80} within one head (rotate-half pairs register-local).
// MODE 0: fp32 row-major Cf. MODE 1: bf16 head layout Cb[h][RO+m][d].
// MODE 2: RoPE-fused bf16 head layout, output scaled by qsc.
// MODE 3: TRANSPOSED bf16 Cb[h][d][RO+m] (V: 4 kv rows -> one 8B store).
#define GBK 64
#define ABUF 8192    // elems per buffer for A (128x64)
#define BBUF 16384   // elems per buffer for B (256x64)
#define BUFE (ABUF + BBUF)

template<int MODE>
__global__ __launch_bounds__(512)
void gemm_bt(const unsigned short* __restrict__ A, const unsigned short* __restrict__ B,
             float* __restrict__ Cf, unsigned short* __restrict__ Cb,
             int M, int N, int K, int RH, int RO, const float2* __restrict__ cs2,
             float qsc) {
  __shared__ unsigned short lds[3 * BUFE];   // 144 KiB
  const int tid = threadIdx.x;
  const int lane = tid & 63;
  const int wave = tid >> 6;
  const int lo = lane & 15, hi = lane >> 4;
  const int wm = wave >> 2, wn = wave & 3;

  // T1: bijective XCD swizzle (nwg % 8 == 0 by construction: 256 blocks)
  const int nwg = gridDim.x * gridDim.y;
  const int orig = blockIdx.y * gridDim.x + blockIdx.x;
  const int wg = (orig & 7) * (nwg >> 3) + (orig >> 3);
  const int bx = wg % gridDim.x, by = wg / gridDim.x;
  const int m0 = by * 128, n0 = bx * 256;

  auto stageA = [&](int kt, int bufe, int g) {
    int j0 = g * 512 + wave * 64;
    int j = j0 + lane;
    int row = j >> 3, cb = j & 7;
    gload_lds16(A + (size_t)(m0 + row) * K + kt * GBK + ((cb ^ (row & 7)) << 3),
                (void*)(lds + bufe + j0 * 8));
  };
  auto stageB = [&](int kt, int bufe, int g) {
    int j0 = g * 512 + wave * 64;
    int j = j0 + lane;
    int row = j >> 3, cb = j & 7;
    gload_lds16(B + (size_t)(n0 + row) * K + kt * GBK + ((cb ^ (row & 7)) << 3),
                (void*)(lds + bufe + ABUF + j0 * 8));
  };

  f32x4 acc[4][4] = {};

  // prologue: tiles 0 and 1 (12 loads in flight)
  stageA(0, 0, 0); stageA(0, 0, 1);
  stageB(0, 0, 0); stageB(0, 0, 1); stageB(0, 0, 2); stageB(0, 0, 3);
  stageA(1, BUFE, 0); stageA(1, BUFE, 1);
  stageB(1, BUFE, 0); stageB(1, BUFE, 1); stageB(1, BUFE, 2); stageB(1, BUFE, 3);

  const int NT = K / GBK;
  const int sa = (lo & 7) << 3;      // read-side swizzle (elems)
  // column-group base: head-pair-local mapping {0,16,64,80}
  const int bbase = (wn >> 1) * 128 + (wn & 1) * 32;
  int bi = 0;

  for (int kt = 0; kt < NT; ++kt) {
    if (kt < NT - 1) { asm volatile("s_waitcnt vmcnt(6)" ::: "memory"); }
    else             { asm volatile("s_waitcnt vmcnt(0)" ::: "memory"); }
    __builtin_amdgcn_sched_barrier(0);
    __builtin_amdgcn_s_barrier();      // raw: no vmcnt(0) drain (T4)
    __builtin_amdgcn_sched_barrier(0);

    const int bufe = bi * BUFE;
    const int nbufe = ((bi + 2 >= 3) ? bi - 1 : bi + 2) * BUFE;
    const bool pre = (kt + 2 < NT);
    const unsigned short* Ab = lds + bufe;
    const unsigned short* Bb = lds + bufe + ABUF;
    const int arow = wm * 64 + lo;
    const int brow = bbase + lo;

    s16x8 af[4], b01[2], b23[2];
    const int c0 = (hi * 8) ^ sa;          // kk=0 swizzled col
    const int c1 = (32 + hi * 8) ^ sa;     // kk=1 swizzled col

    // ---- phase 0: A(kk0) + B01(kk0) reads | stage A(kt+2) | MFMA j=0,1 kk0
#pragma unroll
    for (int i = 0; i < 4; ++i) af[i] = *(const s16x8*)(Ab + (arow + i * 16) * 64 + c0);
    b01[0] = *(const s16x8*)(Bb + (brow +  0) * 64 + c0);
    b01[1] = *(const s16x8*)(Bb + (brow + 16) * 64 + c0);
    if (pre) { stageA(kt + 2, nbufe, 0); stageA(kt + 2, nbufe, 1); }
    asm volatile("s_waitcnt lgkmcnt(0)" ::: "memory");
    __builtin_amdgcn_sched_barrier(0);
    __builtin_amdgcn_s_setprio(1);
#pragma unroll
    for (int i = 0; i < 4; ++i) {
      acc[i][0] = __builtin_amdgcn_mfma_f32_16x16x32_bf16(af[i], b01[0], acc[i][0], 0, 0, 0);
      acc[i][1] = __builtin_amdgcn_mfma_f32_16x16x32_bf16(af[i], b01[1], acc[i][1], 0, 0, 0);
    }
    __builtin_amdgcn_s_setprio(0);

    // ---- phase 1: B23(kk0) reads | stage B(kt+2) g0,g1 | MFMA j=2,3 kk0
    b23[0] = *(const s16x8*)(Bb + (brow + 64) * 64 + c0);
    b23[1] = *(const s16x8*)(Bb + (brow + 80) * 64 + c0);
    if (pre) { stageB(kt + 2, nbufe, 0); stageB(kt + 2, nbufe, 1); }
    asm volatile("s_waitcnt lgkmcnt(0)" ::: "memory");
    __builtin_amdgcn_sched_barrier(0);
    __builtin_amdgcn_s_setprio(1);
#pragma unroll
    for (int i = 0; i < 4; ++i) {
      acc[i][2] = __builtin_amdgcn_mfma_f32_16x16x32_bf16(af[i], b23[0], acc[i][2], 0, 0, 0);
      acc[i][3] = __builtin_amdgcn_mfma_f32_16x16x32_bf16(af[i], b23[1], acc[i][3], 0, 0, 0);
    }
    __builtin_amdgcn_s_setprio(0);

    // ---- phase 2: A(kk1) + B01(kk1) reads | stage B(kt+2) g2,g3 | MFMA j=0,1 kk1
#pragma unroll
    for (int i = 0; i < 4; ++i) af[i] = *(const s16x8*)(Ab + (arow + i * 16) * 64 + c1);
    b01[0] = *(const s16x8*)(Bb + (brow +  0) * 64 + c1);
    b01[1] = *(const s16x8*)(Bb + (brow + 16) * 64 + c1);
    if (pre) { stageB(kt + 2, nbufe, 2); stageB(kt + 2, nbufe, 3); }
    asm volatile("s_waitcnt lgkmcnt(0)" ::: "memory");
    __builtin_amdgcn_sched_barrier(0);
    __builtin_amdgcn_s_setprio(1);
#pragma unroll
    for (int i = 0; i < 4; ++i) {
      acc[i][0] = __builtin_amdgcn_mfma_f32_16x16x32_bf16(af[i], b01[0], acc[i][0], 0, 0, 0);
      acc[i][1] = __builtin_amdgcn_mfma_f32_16x16x32_bf16(af[i], b01[1], acc[i][1], 0, 0, 0);
    }
    __builtin_amdgcn_s_setprio(0);

    // ---- phase 3: B23(kk1) reads | MFMA j=2,3 kk1
    b23[0] = *(const s16x8*)(Bb + (brow + 64) * 64 + c1);
    b23[1] = *(const s16x8*)(Bb + (brow + 80) * 64 + c1);
    asm volatile("s_waitcnt lgkmcnt(0)" ::: "memory");
    __builtin_amdgcn_sched_barrier(0);
    __builtin_amdgcn_s_setprio(1);
#pragma unroll
    for (int i = 0; i < 4; ++i) {
      acc[i][2] = __builtin_amdgcn_mfma_f32_16x16x32_bf16(af[i], b23[0], acc[i][2], 0, 0, 0);
      acc[i][3] = __builtin_amdgcn_mfma_f32_16x16x32_bf16(af[i], b23[1], acc[i][3], 0, 0, 0);
    }
    __builtin_amdgcn_s_setprio(0);

    bi = (bi + 1 == 3) ? 0 : bi + 1;
  }

  // epilogue: col = n0 + bbase + (j>>1)*64 + (j&1)*16 + lo   [remapped groups]
  if (MODE == 2) {
    // RoPE: pair (acc[i][j], acc[i][j+2]) = (x[d], x[d+64]), d < 64; scaled by qsc
#pragma unroll
    for (int i = 0; i < 4; ++i) {
#pragma unroll
      for (int j = 0; j < 2; ++j) {
#pragma unroll
        for (int r = 0; r < 4; ++r) {
          int row = m0 + wm * 64 + i * 16 + hi * 4 + r;
          int col = n0 + bbase + j * 16 + lo;
          int hh = col >> 7, d = col & 127;          // d in [0,64)
          float2 cp = cs2[row * 64 + d];
          float x1 = acc[i][j][r] * qsc, x2 = acc[i][j + 2][r] * qsc;
          size_t base = ((size_t)hh * RH + RO + row) * HD;
          Cb[base + d]      = f2bf(x1 * cp.x - x2 * cp.y);
          Cb[base + d + 64] = f2bf(x2 * cp.x + x1 * cp.y);
        }
      }
    }
  } else if (MODE == 3) {
    // transposed store: Cb[h][d][RO + kv], 4 consecutive kv per reg quad
#pragma unroll
    for (int i = 0; i < 4; ++i) {
#pragma unroll
      for (int j = 0; j < 4; ++j) {
        int rowb = m0 + wm * 64 + i * 16 + hi * 4;
        int col = n0 + bbase + (j >> 1) * 64 + (j & 1) * 16 + lo;
        int hh = col >> 7, d = col & 127;
        u16x4 o4;
#pragma unroll
        for (int r = 0; r < 4; ++r) o4[r] = f2bf(acc[i][j][r]);
        *(u16x4*)(Cb + ((size_t)hh * HD + d) * RH + RO + rowb) = o4;
      }
    }
  } else {
#pragma unroll
    for (int i = 0; i < 4; ++i) {
#pragma unroll
      for (int j = 0; j < 4; ++j) {
#pragma unroll
        for (int r = 0; r < 4; ++r) {
          int row = m0 + wm * 64 + i * 16 + hi * 4 + r;   // C/D: row=(l>>4)*4+reg
          int col = n0 + bbase + (j >> 1) * 64 + (j & 1) * 16 + lo;
          float v = acc[i][j][r];
          if (MODE == 0) {
            Cf[(size_t)row * N + col] = v;
          } else {
            int hh = col >> 7, d = col & 127;
            Cb[((size_t)hh * RH + RO + row) * HD + d] = f2bf(v);
          }
        }
      }
    }
  }
}

// ---------------- flash attention (R7 structure: best measured) ----------------
// Block = (head, one 64-row q-chunk); grid 1024 blocks, heaviest-first,
// 4 heads/XCD. 4 waves x 16 q-rows, KVBLK=64, serial single-buffer staging.
// Q pre-scaled by SC2. Tile types: kt<2 KB (+shiftL), kt==nt-1 diagonal,
// else raw. Vote-based defer-max (T13). l lane-partial, reduced once.
__global__ __launch_bounds__(256)
void attn_kernel(const unsigned short* __restrict__ qh,
                 const unsigned short* __restrict__ kall,
                 const unsigned short* __restrict__ vallT,
                 const float* __restrict__ sshift,
                 unsigned short* __restrict__ ctx) {
  __shared__ __align__(1024) unsigned short Ks[64 * 128];
  __shared__ __align__(1024) unsigned short Vs[128 * 64];
  __shared__ __align__(16)  unsigned short Plds[4][16 * 72];

  int orig = blockIdx.y * 32 + blockIdx.x;
  int wgid = (orig & 7) * 128 + (orig >> 3);   // bijective XCD swizzle (1024 = 8*128)
  int h = wgid >> 5;
  int qc = 31 - (wgid & 31);                   // heaviest chunks launch first

  const int tid = threadIdx.x;
  const int lane = tid & 63;
  const int wave = tid >> 6;
  const int lo = lane & 15;
  const int hi = lane >> 4;
  const float shiftL = sshift[h] * LOG2E;

  const unsigned short* kb = kall + (size_t)h * KVLEN * HD;
  const unsigned short* vtb = vallT + (size_t)h * HD * KVLEN;

  const int m0 = qc * 64;
  const int nt = qc + 3;
  const int qrow = m0 + wave * 16 + hi * 4;

  s16x8 qf[4];
  {
    const unsigned short* qp = qh + ((size_t)h * QLEN + m0 + wave * 16 + lo) * HD + hi * 8;
#pragma unroll
    for (int kc = 0; kc < 4; ++kc) qf[kc] = *(const s16x8*)(qp + kc * 32);
  }

  float m_run[4], l_part[4];
#pragma unroll
  for (int r = 0; r < 4; ++r) { m_run[r] = -1e30f; l_part[r] = 0.f; }
  f32x4 o[8] = {};

  for (int kt = 0; kt < nt; ++kt) {
    const unsigned short* kg = kb + (size_t)kt * 64 * HD;
    const unsigned short* vg = vtb + kt * 64;
    __syncthreads();   // prior tile's readers done before overwrite
#pragma unroll
    for (int it = 0; it < 4; ++it) {
      int j0 = it * 256 + wave * 64;
      int j = j0 + lane;
      int row = j >> 4, cb = j & 15;
      gload_lds16(kg + row * 128 + ((cb ^ (row & 7)) * 8), (void*)(Ks + j0 * 8));
      int d = j >> 3, c = j & 7;
      gload_lds16(vg + (size_t)d * KVLEN + ((c ^ (d & 7)) << 3), (void*)(Vs + j0 * 8));
    }
    __syncthreads();   // implicit vmcnt(0): tile staged & visible

    // S = Q K^T : 16 q-rows x 64 keys per wave (Q pre-scaled by SC2)
    f32x4 s[4] = {};
#pragma unroll
    for (int kc = 0; kc < 4; ++kc) {
#pragma unroll
      for (int g = 0; g < 4; ++g) {
        int key = g * 16 + lo;
        s16x8 kf = *(const s16x8*)(Ks + key * 128 + (((kc * 4 + hi) ^ (key & 7)) * 8));
        s[g] = __builtin_amdgcn_mfma_f32_16x16x32_bf16(qf[kc], kf, s[g], 0, 0, 0);
      }
    }

    // tile-type adjustment (uniform branches)
    if (kt < 2) {
#pragma unroll
      for (int g = 0; g < 4; ++g)
#pragma unroll
        for (int r = 0; r < 4; ++r) s[g][r] += shiftL;
    } else if (kt == nt - 1) {
      const int kvbase = kt * 64;
#pragma unroll
      for (int r = 0; r < 4; ++r) {
        int qr = qrow + r;
#pragma unroll
        for (int g = 0; g < 4; ++g) {
          int kv = kvbase + g * 16 + lo;
          s[g][r] = (kv - NTOPK > qr) ? PADV : s[g][r];
        }
      }
    }

    // vote-based defer-max
    float mx[4];
    bool need = false;
#pragma unroll
    for (int r = 0; r < 4; ++r) {
      mx[r] = fmaxf(fmaxf(s[0][r], s[1][r]), fmaxf(s[2][r], s[3][r]));
      need = need || (mx[r] > m_run[r] + DEFER_THR);
    }
    if (__any((int)need)) {
#pragma unroll
      for (int off = 1; off < 16; off <<= 1)
#pragma unroll
        for (int r = 0; r < 4; ++r) mx[r] = fmaxf(mx[r], __shfl_xor(mx[r], off, 64));
#pragma unroll
      for (int r = 0; r < 4; ++r) {
        float mn = fmaxf(m_run[r], mx[r]);
        float alpha = __builtin_amdgcn_exp2f(m_run[r] - mn);
        m_run[r] = mn;
        l_part[r] *= alpha;
#pragma unroll
        for (int db = 0; db < 8; ++db) o[db][r] *= alpha;
      }
    }

    // p = exp2(s - m), lane-partial l, P -> LDS
#pragma unroll
    for (int r = 0; r < 4; ++r) {
#pragma unroll
      for (int g = 0; g < 4; ++g) {
        float p = __builtin_amdgcn_exp2f(s[g][r] - m_run[r]);
        l_part[r] += p;
        Plds[wave][(hi * 4 + r) * 72 + g * 16 + lo] = f2bf(p);
      }
    }

    // PV: A = P (same-wave LDS round trip), B = V^T single b128 per frag
    s16x8 pf0 = *(const s16x8*)(&Plds[wave][lo * 72 + hi * 8]);
    s16x8 pf1 = *(const s16x8*)(&Plds[wave][lo * 72 + 32 + hi * 8]);
#pragma unroll
    for (int db = 0; db < 8; ++db) {
      int d = db * 16 + lo;
      s16x8 vf0 = *(const s16x8*)(Vs + d * 64 + ((hi       ^ (d & 7)) << 3));
      s16x8 vf1 = *(const s16x8*)(Vs + d * 64 + (((4 + hi) ^ (d & 7)) << 3));
      o[db] = __builtin_amdgcn_mfma_f32_16x16x32_bf16(pf0, vf0, o[db], 0, 0, 0);
      o[db] = __builtin_amdgcn_mfma_f32_16x16x32_bf16(pf1, vf1, o[db], 0, 0, 0);
    }
  } // kt

  // reduce lane-partial l across the 16 lo lanes (once per block)
#pragma unroll
  for (int off = 1; off < 16; off <<= 1)
#pragma unroll
    for (int r = 0; r < 4; ++r) l_part[r] += __shfl_xor(l_part[r], off, 64);

  float rinv[4];
#pragma unroll
  for (int r = 0; r < 4; ++r) rinv[r] = __builtin_amdgcn_rcpf(l_part[r]);

  // normalize + write ctx[q][h*128+d] bf16
#pragma unroll
  for (int db = 0; db < 8; ++db) {
#pragma unroll
    for (int r = 0; r < 4; ++r) {
      int row = qrow + r;
      int col = h * HD + db * 16 + lo;
      ctx[(size_t)row * HID + col] = f2bf(o[db][r] * rinv[r]);
    }
  }
}

// ---------------- launch ----------------

extern "C" void kernel_launch(void* const* d_in, const int* in_sizes, int n_in,
                              void* d_out, int out_size, void* d_ws, size_t ws_size,
                              hipStream_t stream) {
  const float* hidden    = (const float*)d_in[0];
  const int*   pos       = (const int*)d_in[2];
  const float* kb_keys   = (const float*)d_in[3];
  const float* kb_values = (const float*)d_in[4];
  const float* Wq        = (const float*)d_in[5];
  const float* Wq2       = (const float*)d_in[6];
  const float* Wk        = (const float*)d_in[7];
  const float* Wv        = (const float*)d_in[8];
  const float* Wo        = (const float*)d_in[9];
  const float* sshift    = (const float*)d_in[10];
  float* out = (float*)d_out;

  char* ws = (char*)d_ws;
  size_t off = 0;
  auto alloc = [&](size_t bytes) { char* p = ws + off; off += (bytes + 255) & ~(size_t)255; return p; };
  unsigned short* hidden_bf = (unsigned short*)alloc((size_t)QLEN * HID * 2);
  unsigned short* wbuf      = (unsigned short*)alloc((size_t)HID * HID * 2);
  unsigned short* qbf       = (unsigned short*)alloc((size_t)NH * QLEN * HD * 2);
  unsigned short* kallp     = (unsigned short*)alloc((size_t)NH * KVLEN * HD * 2);
  unsigned short* vallT     = (unsigned short*)alloc((size_t)NH * HD * KVLEN * 2);
  unsigned short* ctx       = (unsigned short*)alloc((size_t)QLEN * HID * 2);
  float2*         cs2       = (float2*)alloc((size_t)QLEN * 64 * 8);
  float*          part      = (float*)alloc((size_t)16 * HID * 4);
  float*          hsum      = (float*)alloc(HID * 4);
  float*          qs        = (float*)alloc(HID * 4);
  float*          scores    = (float*)alloc(KBLEN * 4);
  int*            idx       = (int*)alloc(NTOPK * 4);

  dim3 blk(256);

  k_cast<<<QLEN * HID / 4 / 256, blk, 0, stream>>>(hidden, hidden_bf, QLEN * HID / 4);
  k_rowsum_p<<<dim3(HID / 256, 16), blk, 0, stream>>>(hidden, part);
  k_rowsum_r<<<HID / 256, blk, 0, stream>>>(part, hsum);
  k_dotrows<<<HID / 4, blk, 0, stream>>>(hsum, Wq2, qs, HID, 1.0f);
  k_dotrows<<<KBLEN / 4, blk, 0, stream>>>(qs, kb_keys, scores, HID, SCALE);
  k_topk<<<1, KBLEN, 0, stream>>>(scores, idx);
  k_cs<<<QLEN * 64 / 256, blk, 0, stream>>>(pos, cs2);

  dim3 ggrid(HID / 256, QLEN / 128);  // (16, 16) = 256 blocks, 1/CU
  dim3 gblk(512);
  int wcast_blocks = HID * HID / 4 / 256;

  // Q projection + RoPE (pre-scaled by SC2) -> qbf[h][q][d]
  k_cast<<<wcast_blocks, blk, 0, stream>>>(Wq, wbuf, HID * HID / 4);
  gemm_bt<2><<<ggrid, gblk, 0, stream>>>(hidden_bf, wbuf, nullptr, qbf, QLEN, HID, HID, QLEN, 0, cs2, (float)SC2);
  // K projection + RoPE -> k_all[h][128+q][d]
  k_cast<<<wcast_blocks, blk, 0, stream>>>(Wk, wbuf, HID * HID / 4);
  gemm_bt<2><<<ggrid, gblk, 0, stream>>>(hidden_bf, wbuf, nullptr, kallp, QLEN, HID, HID, KVLEN, NTOPK, cs2, 1.0f);
  // V projection -> v_all^T[h][d][128+q]
  k_cast<<<wcast_blocks, blk, 0, stream>>>(Wv, wbuf, HID * HID / 4);
  gemm_bt<3><<<ggrid, gblk, 0, stream>>>(hidden_bf, wbuf, nullptr, vallT, QLEN, HID, HID, KVLEN, NTOPK, cs2, 1.0f);

  // gather selected KB keys/values into k_all[:, :128] / v_all^T[:, :, :128]
  k_gather<<<NH * NTOPK * HD / 256, blk, 0, stream>>>(kb_keys, kb_values, idx, kallp, vallT);

  // flash attention -> ctx bf16 [q][h*128+d]
  dim3 agrid(32, NH);   // 1024 single-chunk blocks
  attn_kernel<<<agrid, blk, 0, stream>>>(qbf, kallp, vallT, sshift, ctx);

  // output projection -> d_out fp32
  k_cast<<<wcast_blocks, blk, 0, stream>>>(Wo, wbuf, HID * HID / 4);
  gemm_bt<0><<<ggrid, gblk, 0, stream>>>(ctx, wbuf, out, nullptr, QLEN, HID, HID, 0, 0, cs2, 1.0f);
}

// Round 15
// 561.653 us; speedup vs baseline: 1.7442x; 1.0068x over previous
//
#include <hip/hip_runtime.h>
#include <stdint.h>
#include <stddef.h>

#define NH 32
#define HD 128
#define HID 4096
#define QLEN 2048
#define KBLEN 1024
#define NTOPK 128
#define KVLEN 2176   // NTOPK + QLEN
#define PADV -1e9f
#define SCALE 0.08838834764831845f
#define LOG2E 1.4426950408889634f
#define SC2 (SCALE * LOG2E)          // score scale in log2 domain (folded into Q)
#define DEFER_THR 8.0f

typedef __attribute__((ext_vector_type(4))) float f32x4;
typedef __attribute__((ext_vector_type(4))) unsigned short u16x4;
typedef __attribute__((ext_vector_type(8))) short s16x8;

typedef const __attribute__((address_space(1))) void* gas1_t;
typedef __attribute__((address_space(3))) void* las3_t;

__device__ __forceinline__ void gload_lds16(const void* g, void* l) {
  __builtin_amdgcn_global_load_lds((gas1_t)g, (las3_t)l, 16, 0, 0);
}

__device__ __forceinline__ unsigned short f2bf(float x) {
  union { float f; unsigned u; } z; z.f = x;
  unsigned r = z.u + 0x7fffu + ((z.u >> 16) & 1u);
  return (unsigned short)(r >> 16);
}

// ---------------- small prep kernels ----------------

__global__ void k_cast(const float* __restrict__ src, unsigned short* __restrict__ dst, int n4) {
  int i = blockIdx.x * 256 + threadIdx.x;
  if (i >= n4) return;
  f32x4 v = ((const f32x4*)src)[i];
  u16x4 o;
  o[0] = f2bf(v[0]); o[1] = f2bf(v[1]); o[2] = f2bf(v[2]); o[3] = f2bf(v[3]);
  ((u16x4*)dst)[i] = o;
}

// dual cast: two weights in one launch (grid exactly 2*n4each/256 blocks)
__global__ void k_cast2(const float* __restrict__ s0, const float* __restrict__ s1,
                        unsigned short* __restrict__ d0, unsigned short* __restrict__ d1,
                        int n4each) {
  int i = blockIdx.x * 256 + threadIdx.x;
  int grp = (i >= n4each);
  const float* s = grp ? s1 : s0;
  unsigned short* d = grp ? d1 : d0;
  int j = grp ? (i - n4each) : i;
  f32x4 v = ((const f32x4*)s)[j];
  u16x4 o;
  o[0] = f2bf(v[0]); o[1] = f2bf(v[1]); o[2] = f2bf(v[2]); o[3] = f2bf(v[3]);
  ((u16x4*)d)[j] = o;
}

// column sums of hidden: two-stage, deterministic (no atomics -> top-k stable)
__global__ void k_rowsum_p(const float* __restrict__ x, float* __restrict__ part) {
  int d = blockIdx.x * 256 + threadIdx.x;
  int q0 = blockIdx.y * 128;
  float acc = 0.f;
  for (int q = q0; q < q0 + 128; ++q) acc += x[(size_t)q * HID + d];
  part[(size_t)blockIdx.y * HID + d] = acc;
}
__global__ void k_rowsum_r(const float* __restrict__ part, float* __restrict__ out) {
  int d = blockIdx.x * 256 + threadIdx.x;
  float acc = 0.f;
#pragma unroll
  for (int i = 0; i < 16; ++i) acc += part[(size_t)i * HID + d];
  out[d] = acc;
}

// out[n] = s * dot(vec, mat[n,:]) ; one wave per n, 4 waves/block
__global__ void k_dotrows(const float* __restrict__ vec, const float* __restrict__ mat,
                          float* __restrict__ out, int K, float s) {
  int n = blockIdx.x * 4 + (threadIdx.x >> 6);
  int lane = threadIdx.x & 63;
  const float* row = mat + (size_t)n * K;
  float acc = 0.f;
  for (int j = lane; j < K; j += 64) acc += vec[j] * row[j];
#pragma unroll
  for (int off = 32; off > 0; off >>= 1) acc += __shfl_down(acc, off, 64);
  if (lane == 0) out[n] = acc * s;
}

// stable top-k by rank counting (tie-break: lower index wins, matches lax.top_k)
__global__ void k_topk(const float* __restrict__ scores, int* __restrict__ idx) {
  __shared__ float s[KBLEN];
  int t = threadIdx.x;
  s[t] = scores[t];
  __syncthreads();
  float mine = s[t];
  int rank = 0;
  for (int j = 0; j < KBLEN; ++j) {
    float v = s[j];
    rank += (v > mine) || (v == mine && j < t);
  }
  if (rank < NTOPK) idx[rank] = t;
}

// cos/sin table, interleaved pairs: cs[p*64+i] = {cos, sin} of pos_p * invf_i
__global__ void k_cs(const int* __restrict__ pos_ids, float2* __restrict__ cs) {
  int t = blockIdx.x * 256 + threadIdx.x;   // QLEN*64 threads
  int p = t >> 6, i = t & 63;
  float pos = (float)pos_ids[p];
  float invf = powf(10000.0f, -(float)i / 64.0f);
  float a = pos * invf;
  cs[p * 64 + i] = make_float2(cosf(a), sinf(a));
}

// gather selected KB rows: K -> kall[h][i][d], V -> vallT[h][d][i] (transposed)
__global__ void k_gather(const float* __restrict__ kbk, const float* __restrict__ kbv,
                         const int* __restrict__ idx,
                         unsigned short* __restrict__ kall, unsigned short* __restrict__ vallT) {
  int t = blockIdx.x * 256 + threadIdx.x;   // NH*NTOPK*HD threads
  int d = t & 127;
  int i = (t >> 7) & 127;
  int hh = t >> 14;
  int kr = idx[i];
  size_t src = (size_t)kr * HID + hh * HD + d;
  kall[((size_t)hh * KVLEN + i) * HD + d] = f2bf(kbk[src]);
  vallT[((size_t)hh * HD + d) * KVLEN + i] = f2bf(kbv[src]);
}

// ---------------- bf16 MFMA GEMM: C[m,n] = sum_k A[m,k]*B[n,k] ----------------
// Pipelined template (T1+T2+T3+T4+T5): BM=128, BN=256, BK=64, 512 threads =
// 8 waves (2M x 4N), per-wave 64x64 output. 3 LDS buffers, ONE raw s_barrier
// + ONE counted vmcnt(6) per K-tile. Wave's 4 column groups remapped to
// {d, d+16, d+64, d+80} within one head (rotate-half pairs register-local).
// MODE 0: fp32 row-major Cf. MODE 1: bf16 head layout Cb[h][RO+m][d].
// MODE 2: RoPE-fused bf16 head layout, output scaled by qsc.
// MODE 3: TRANSPOSED bf16 Cb[h][d][RO+m] (V: 4 kv rows -> one 8B store).
#define GBK 64
#define ABUF 8192    // elems per buffer for A (128x64)
#define BBUF 16384   // elems per buffer for B (256x64)
#define BUFE (ABUF + BBUF)

#define GEMM_MAIN_LOOP                                                         \
  f32x4 acc[4][4] = {};                                                        \
  stageA(0, 0, 0); stageA(0, 0, 1);                                            \
  stageB(0, 0, 0); stageB(0, 0, 1); stageB(0, 0, 2); stageB(0, 0, 3);          \
  stageA(1, BUFE, 0); stageA(1, BUFE, 1);                                      \
  stageB(1, BUFE, 0); stageB(1, BUFE, 1); stageB(1, BUFE, 2); stageB(1, BUFE, 3); \
  const int NT = K / GBK;                                                      \
  const int sa = (lo & 7) << 3;                                                \
  const int bbase = (wn >> 1) * 128 + (wn & 1) * 32;                           \
  int bi = 0;                                                                  \
  for (int kt = 0; kt < NT; ++kt) {                                            \
    if (kt < NT - 1) { asm volatile("s_waitcnt vmcnt(6)" ::: "memory"); }      \
    else             { asm volatile("s_waitcnt vmcnt(0)" ::: "memory"); }      \
    __builtin_amdgcn_sched_barrier(0);                                         \
    __builtin_amdgcn_s_barrier();                                              \
    __builtin_amdgcn_sched_barrier(0);                                         \
    const int bufe = bi * BUFE;                                                \
    const int nbufe = ((bi + 2 >= 3) ? bi - 1 : bi + 2) * BUFE;                \
    const bool pre = (kt + 2 < NT);                                            \
    const unsigned short* Ab = lds + bufe;                                     \
    const unsigned short* Bb = lds + bufe + ABUF;                              \
    const int arow = wm * 64 + lo;                                             \
    const int brow = bbase + lo;                                               \
    s16x8 af[4], b01[2], b23[2];                                               \
    const int c0 = (hi * 8) ^ sa;                                              \
    const int c1 = (32 + hi * 8) ^ sa;                                         \
    _Pragma("unroll")                                                          \
    for (int i = 0; i < 4; ++i) af[i] = *(const s16x8*)(Ab + (arow + i * 16) * 64 + c0); \
    b01[0] = *(const s16x8*)(Bb + (brow +  0) * 64 + c0);                      \
    b01[1] = *(const s16x8*)(Bb + (brow + 16) * 64 + c0);                      \
    if (pre) { stageA(kt + 2, nbufe, 0); stageA(kt + 2, nbufe, 1); }           \
    asm volatile("s_waitcnt lgkmcnt(0)" ::: "memory");                         \
    __builtin_amdgcn_sched_barrier(0);                                         \
    __builtin_amdgcn_s_setprio(1);                                             \
    _Pragma("unroll")                                                          \
    for (int i = 0; i < 4; ++i) {                                              \
      acc[i][0] = __builtin_amdgcn_mfma_f32_16x16x32_bf16(af[i], b01[0], acc[i][0], 0, 0, 0); \
      acc[i][1] = __builtin_amdgcn_mfma_f32_16x16x32_bf16(af[i], b01[1], acc[i][1], 0, 0, 0); \
    }                                                                          \
    __builtin_amdgcn_s_setprio(0);                                             \
    b23[0] = *(const s16x8*)(Bb + (brow + 64) * 64 + c0);                      \
    b23[1] = *(const s16x8*)(Bb + (brow + 80) * 64 + c0);                      \
    if (pre) { stageB(kt + 2, nbufe, 0); stageB(kt + 2, nbufe, 1); }           \
    asm volatile("s_waitcnt lgkmcnt(0)" ::: "memory");                         \
    __builtin_amdgcn_sched_barrier(0);                                         \
    __builtin_amdgcn_s_setprio(1);                                             \
    _Pragma("unroll")                                                          \
    for (int i = 0; i < 4; ++i) {                                              \
      acc[i][2] = __builtin_amdgcn_mfma_f32_16x16x32_bf16(af[i], b23[0], acc[i][2], 0, 0, 0); \
      acc[i][3] = __builtin_amdgcn_mfma_f32_16x16x32_bf16(af[i], b23[1], acc[i][3], 0, 0, 0); \
    }                                                                          \
    __builtin_amdgcn_s_setprio(0);                                             \
    _Pragma("unroll")                                                          \
    for (int i = 0; i < 4; ++i) af[i] = *(const s16x8*)(Ab + (arow + i * 16) * 64 + c1); \
    b01[0] = *(const s16x8*)(Bb + (brow +  0) * 64 + c1);                      \
    b01[1] = *(const s16x8*)(Bb + (brow + 16) * 64 + c1);                      \
    if (pre) { stageB(kt + 2, nbufe, 2); stageB(kt + 2, nbufe, 3); }           \
    asm volatile("s_waitcnt lgkmcnt(0)" ::: "memory");                         \
    __builtin_amdgcn_sched_barrier(0);                                         \
    __builtin_amdgcn_s_setprio(1);                                             \
    _Pragma("unroll")                                                          \
    for (int i = 0; i < 4; ++i) {                                              \
      acc[i][0] = __builtin_amdgcn_mfma_f32_16x16x32_bf16(af[i], b01[0], acc[i][0], 0, 0, 0); \
      acc[i][1] = __builtin_amdgcn_mfma_f32_16x16x32_bf16(af[i], b01[1], acc[i][1], 0, 0, 0); \
    }                                                                          \
    __builtin_amdgcn_s_setprio(0);                                             \
    b23[0] = *(const s16x8*)(Bb + (brow + 64) * 64 + c1);                      \
    b23[1] = *(const s16x8*)(Bb + (brow + 80) * 64 + c1);                      \
    asm volatile("s_waitcnt lgkmcnt(0)" ::: "memory");                         \
    __builtin_amdgcn_sched_barrier(0);                                         \
    __builtin_amdgcn_s_setprio(1);                                             \
    _Pragma("unroll")                                                          \
    for (int i = 0; i < 4; ++i) {                                              \
      acc[i][2] = __builtin_amdgcn_mfma_f32_16x16x32_bf16(af[i], b23[0], acc[i][2], 0, 0, 0); \
      acc[i][3] = __builtin_amdgcn_mfma_f32_16x16x32_bf16(af[i], b23[1], acc[i][3], 0, 0, 0); \
    }                                                                          \
    __builtin_amdgcn_s_setprio(0);                                             \
    bi = (bi + 1 == 3) ? 0 : bi + 1;                                           \
  }

template<int MODE>
__global__ __launch_bounds__(512)
void gemm_bt(const unsigned short* __restrict__ A, const unsigned short* __restrict__ B,
             float* __restrict__ Cf, unsigned short* __restrict__ Cb,
             int M, int N, int K, int RH, int RO, const float2* __restrict__ cs2,
             float qsc) {
  __shared__ unsigned short lds[3 * BUFE];   // 144 KiB
  const int tid = threadIdx.x;
  const int lane = tid & 63;
  const int wave = tid >> 6;
  const int lo = lane & 15, hi = lane >> 4;
  const int wm = wave >> 2, wn = wave & 3;

  // T1: bijective XCD swizzle (nwg % 8 == 0 by construction: 256 blocks)
  const int nwg = gridDim.x * gridDim.y;
  const int orig = blockIdx.y * gridDim.x + blockIdx.x;
  const int wg = (orig & 7) * (nwg >> 3) + (orig >> 3);
  const int bx = wg % gridDim.x, by = wg / gridDim.x;
  const int m0 = by * 128, n0 = bx * 256;

  auto stageA = [&](int kt, int bufe, int g) {
    int j0 = g * 512 + wave * 64;
    int j = j0 + lane;
    int row = j >> 3, cb = j & 7;
    gload_lds16(A + (size_t)(m0 + row) * K + kt * GBK + ((cb ^ (row & 7)) << 3),
                (void*)(lds + bufe + j0 * 8));
  };
  auto stageB = [&](int kt, int bufe, int g) {
    int j0 = g * 512 + wave * 64;
    int j = j0 + lane;
    int row = j >> 3, cb = j & 7;
    gload_lds16(B + (size_t)(n0 + row) * K + kt * GBK + ((cb ^ (row & 7)) << 3),
                (void*)(lds + bufe + ABUF + j0 * 8));
  };

  GEMM_MAIN_LOOP

  // epilogue: col = n0 + bbase + (j>>1)*64 + (j&1)*16 + lo   [remapped groups]
  if (MODE == 2) {
#pragma unroll
    for (int i = 0; i < 4; ++i) {
#pragma unroll
      for (int j = 0; j < 2; ++j) {
#pragma unroll
        for (int r = 0; r < 4; ++r) {
          int row = m0 + wm * 64 + i * 16 + hi * 4 + r;
          int col = n0 + bbase + j * 16 + lo;
          int hh = col >> 7, d = col & 127;          // d in [0,64)
          float2 cp = cs2[row * 64 + d];
          float x1 = acc[i][j][r] * qsc, x2 = acc[i][j + 2][r] * qsc;
          size_t base = ((size_t)hh * RH + RO + row) * HD;
          Cb[base + d]      = f2bf(x1 * cp.x - x2 * cp.y);
          Cb[base + d + 64] = f2bf(x2 * cp.x + x1 * cp.y);
        }
      }
    }
  } else if (MODE == 3) {
#pragma unroll
    for (int i = 0; i < 4; ++i) {
#pragma unroll
      for (int j = 0; j < 4; ++j) {
        int rowb = m0 + wm * 64 + i * 16 + hi * 4;
        int col = n0 + bbase + (j >> 1) * 64 + (j & 1) * 16 + lo;
        int hh = col >> 7, d = col & 127;
        u16x4 o4;
#pragma unroll
        for (int r = 0; r < 4; ++r) o4[r] = f2bf(acc[i][j][r]);
        *(u16x4*)(Cb + ((size_t)hh * HD + d) * RH + RO + rowb) = o4;
      }
    }
  } else {
#pragma unroll
    for (int i = 0; i < 4; ++i) {
#pragma unroll
      for (int j = 0; j < 4; ++j) {
#pragma unroll
        for (int r = 0; r < 4; ++r) {
          int row = m0 + wm * 64 + i * 16 + hi * 4 + r;   // C/D: row=(l>>4)*4+reg
          int col = n0 + bbase + (j >> 1) * 64 + (j & 1) * 16 + lo;
          float v = acc[i][j][r];
          if (MODE == 0) {
            Cf[(size_t)row * N + col] = v;
          } else {
            int hh = col >> 7, d = col & 127;
            Cb[((size_t)hh * RH + RO + row) * HD + d] = f2bf(v);
          }
        }
      }
    }
  }
}

// Merged Q+K projection: 512 blocks; after XCD swizzle, grp = wg>>8 selects
// weight/dst (Q on XCDs 0-3, K on 4-7; B-panel L2 locality preserved).
// Body identical to gemm_bt MODE2.
__global__ __launch_bounds__(512)
void gemm_qk(const unsigned short* __restrict__ A,
             const unsigned short* __restrict__ B0, const unsigned short* __restrict__ B1,
             unsigned short* __restrict__ C0, unsigned short* __restrict__ C1,
             const float2* __restrict__ cs2) {
  __shared__ unsigned short lds[3 * BUFE];   // 144 KiB
  const int tid = threadIdx.x;
  const int lane = tid & 63;
  const int wave = tid >> 6;
  const int lo = lane & 15, hi = lane >> 4;
  const int wm = wave >> 2, wn = wave & 3;

  const int nwg = gridDim.x * gridDim.y;                 // 512
  const int orig = blockIdx.y * gridDim.x + blockIdx.x;
  const int wg = (orig & 7) * (nwg >> 3) + (orig >> 3);
  const int grp = wg >> 8;
  const int rem = wg & 255;
  const int bx = rem & 15, by = rem >> 4;
  const int m0 = by * 128, n0 = bx * 256;

  const unsigned short* B = grp ? B1 : B0;
  unsigned short* Cb = grp ? C1 : C0;
  const float qsc = grp ? 1.0f : (float)SC2;
  const int RH = grp ? KVLEN : QLEN;
  const int RO = grp ? NTOPK : 0;
  const int K = HID;

  auto stageA = [&](int kt, int bufe, int g) {
    int j0 = g * 512 + wave * 64;
    int j = j0 + lane;
    int row = j >> 3, cb = j & 7;
    gload_lds16(A + (size_t)(m0 + row) * K + kt * GBK + ((cb ^ (row & 7)) << 3),
                (void*)(lds + bufe + j0 * 8));
  };
  auto stageB = [&](int kt, int bufe, int g) {
    int j0 = g * 512 + wave * 64;
    int j = j0 + lane;
    int row = j >> 3, cb = j & 7;
    gload_lds16(B + (size_t)(n0 + row) * K + kt * GBK + ((cb ^ (row & 7)) << 3),
                (void*)(lds + bufe + ABUF + j0 * 8));
  };

  GEMM_MAIN_LOOP

  // RoPE epilogue (MODE2)
#pragma unroll
  for (int i = 0; i < 4; ++i) {
#pragma unroll
    for (int j = 0; j < 2; ++j) {
#pragma unroll
      for (int r = 0; r < 4; ++r) {
        int row = m0 + wm * 64 + i * 16 + hi * 4 + r;
        int col = n0 + bbase + j * 16 + lo;
        int hh = col >> 7, d = col & 127;          // d in [0,64)
        float2 cp = cs2[row * 64 + d];
        float x1 = acc[i][j][r] * qsc, x2 = acc[i][j + 2][r] * qsc;
        size_t base = ((size_t)hh * RH + RO + row) * HD;
        Cb[base + d]      = f2bf(x1 * cp.x - x2 * cp.y);
        Cb[base + d + 64] = f2bf(x2 * cp.x + x1 * cp.y);
      }
    }
  }
}

// ---------------- flash attention (R7 structure: best measured) ----------------
// Block = (head, one 64-row q-chunk); grid 1024 blocks, heaviest-first,
// 4 heads/XCD. 4 waves x 16 q-rows, KVBLK=64, serial single-buffer staging.
// Q pre-scaled by SC2. Tile types: kt<2 KB (+shiftL), kt==nt-1 diagonal,
// else raw. Vote-based defer-max (T13). l lane-partial, reduced once.
__global__ __launch_bounds__(256)
void attn_kernel(const unsigned short* __restrict__ qh,
                 const unsigned short* __restrict__ kall,
                 const unsigned short* __restrict__ vallT,
                 const float* __restrict__ sshift,
                 unsigned short* __restrict__ ctx) {
  __shared__ __align__(1024) unsigned short Ks[64 * 128];
  __shared__ __align__(1024) unsigned short Vs[128 * 64];
  __shared__ __align__(16)  unsigned short Plds[4][16 * 72];

  int orig = blockIdx.y * 32 + blockIdx.x;
  int wgid = (orig & 7) * 128 + (orig >> 3);   // bijective XCD swizzle (1024 = 8*128)
  int h = wgid >> 5;
  int qc = 31 - (wgid & 31);                   // heaviest chunks launch first

  const int tid = threadIdx.x;
  const int lane = tid & 63;
  const int wave = tid >> 6;
  const int lo = lane & 15;
  const int hi = lane >> 4;
  const float shiftL = sshift[h] * LOG2E;

  const unsigned short* kb = kall + (size_t)h * KVLEN * HD;
  const unsigned short* vtb = vallT + (size_t)h * HD * KVLEN;

  const int m0 = qc * 64;
  const int nt = qc + 3;
  const int qrow = m0 + wave * 16 + hi * 4;

  s16x8 qf[4];
  {
    const unsigned short* qp = qh + ((size_t)h * QLEN + m0 + wave * 16 + lo) * HD + hi * 8;
#pragma unroll
    for (int kc = 0; kc < 4; ++kc) qf[kc] = *(const s16x8*)(qp + kc * 32);
  }

  float m_run[4], l_part[4];
#pragma unroll
  for (int r = 0; r < 4; ++r) { m_run[r] = -1e30f; l_part[r] = 0.f; }
  f32x4 o[8] = {};

  for (int kt = 0; kt < nt; ++kt) {
    const unsigned short* kg = kb + (size_t)kt * 64 * HD;
    const unsigned short* vg = vtb + kt * 64;
    __syncthreads();   // prior tile's readers done before overwrite
#pragma unroll
    for (int it = 0; it < 4; ++it) {
      int j0 = it * 256 + wave * 64;
      int j = j0 + lane;
      int row = j >> 4, cb = j & 15;
      gload_lds16(kg + row * 128 + ((cb ^ (row & 7)) * 8), (void*)(Ks + j0 * 8));
      int d = j >> 3, c = j & 7;
      gload_lds16(vg + (size_t)d * KVLEN + ((c ^ (d & 7)) << 3), (void*)(Vs + j0 * 8));
    }
    __syncthreads();   // implicit vmcnt(0): tile staged & visible

    // S = Q K^T : 16 q-rows x 64 keys per wave (Q pre-scaled by SC2)
    f32x4 s[4] = {};
#pragma unroll
    for (int kc = 0; kc < 4; ++kc) {
#pragma unroll
      for (int g = 0; g < 4; ++g) {
        int key = g * 16 + lo;
        s16x8 kf = *(const s16x8*)(Ks + key * 128 + (((kc * 4 + hi) ^ (key & 7)) * 8));
        s[g] = __builtin_amdgcn_mfma_f32_16x16x32_bf16(qf[kc], kf, s[g], 0, 0, 0);
      }
    }

    // tile-type adjustment (uniform branches)
    if (kt < 2) {
#pragma unroll
      for (int g = 0; g < 4; ++g)
#pragma unroll
        for (int r = 0; r < 4; ++r) s[g][r] += shiftL;
    } else if (kt == nt - 1) {
      const int kvbase = kt * 64;
#pragma unroll
      for (int r = 0; r < 4; ++r) {
        int qr = qrow + r;
#pragma unroll
        for (int g = 0; g < 4; ++g) {
          int kv = kvbase + g * 16 + lo;
          s[g][r] = (kv - NTOPK > qr) ? PADV : s[g][r];
        }
      }
    }

    // vote-based defer-max
    float mx[4];
    bool need = false;
#pragma unroll
    for (int r = 0; r < 4; ++r) {
      mx[r] = fmaxf(fmaxf(s[0][r], s[1][r]), fmaxf(s[2][r], s[3][r]));
      need = need || (mx[r] > m_run[r] + DEFER_THR);
    }
    if (__any((int)need)) {
#pragma unroll
      for (int off = 1; off < 16; off <<= 1)
#pragma unroll
        for (int r = 0; r < 4; ++r) mx[r] = fmaxf(mx[r], __shfl_xor(mx[r], off, 64));
#pragma unroll
      for (int r = 0; r < 4; ++r) {
        float mn = fmaxf(m_run[r], mx[r]);
        float alpha = __builtin_amdgcn_exp2f(m_run[r] - mn);
        m_run[r] = mn;
        l_part[r] *= alpha;
#pragma unroll
        for (int db = 0; db < 8; ++db) o[db][r] *= alpha;
      }
    }

    // p = exp2(s - m), lane-partial l, P -> LDS
#pragma unroll
    for (int r = 0; r < 4; ++r) {
#pragma unroll
      for (int g = 0; g < 4; ++g) {
        float p = __builtin_amdgcn_exp2f(s[g][r] - m_run[r]);
        l_part[r] += p;
        Plds[wave][(hi * 4 + r) * 72 + g * 16 + lo] = f2bf(p);
      }
    }

    // PV: A = P (same-wave LDS round trip), B = V^T single b128 per frag
    s16x8 pf0 = *(const s16x8*)(&Plds[wave][lo * 72 + hi * 8]);
    s16x8 pf1 = *(const s16x8*)(&Plds[wave][lo * 72 + 32 + hi * 8]);
#pragma unroll
    for (int db = 0; db < 8; ++db) {
      int d = db * 16 + lo;
      s16x8 vf0 = *(const s16x8*)(Vs + d * 64 + ((hi       ^ (d & 7)) << 3));
      s16x8 vf1 = *(const s16x8*)(Vs + d * 64 + (((4 + hi) ^ (d & 7)) << 3));
      o[db] = __builtin_amdgcn_mfma_f32_16x16x32_bf16(pf0, vf0, o[db], 0, 0, 0);
      o[db] = __builtin_amdgcn_mfma_f32_16x16x32_bf16(pf1, vf1, o[db], 0, 0, 0);
    }
  } // kt

  // reduce lane-partial l across the 16 lo lanes (once per block)
#pragma unroll
  for (int off = 1; off < 16; off <<= 1)
#pragma unroll
    for (int r = 0; r < 4; ++r) l_part[r] += __shfl_xor(l_part[r], off, 64);

  float rinv[4];
#pragma unroll
  for (int r = 0; r < 4; ++r) rinv[r] = __builtin_amdgcn_rcpf(l_part[r]);

  // normalize + write ctx[q][h*128+d] bf16
#pragma unroll
  for (int db = 0; db < 8; ++db) {
#pragma unroll
    for (int r = 0; r < 4; ++r) {
      int row = qrow + r;
      int col = h * HD + db * 16 + lo;
      ctx[(size_t)row * HID + col] = f2bf(o[db][r] * rinv[r]);
    }
  }
}

// ---------------- launch ----------------

extern "C" void kernel_launch(void* const* d_in, const int* in_sizes, int n_in,
                              void* d_out, int out_size, void* d_ws, size_t ws_size,
                              hipStream_t stream) {
  const float* hidden    = (const float*)d_in[0];
  const int*   pos       = (const int*)d_in[2];
  const float* kb_keys   = (const float*)d_in[3];
  const float* kb_values = (const float*)d_in[4];
  const float* Wq        = (const float*)d_in[5];
  const float* Wq2       = (const float*)d_in[6];
  const float* Wk        = (const float*)d_in[7];
  const float* Wv        = (const float*)d_in[8];
  const float* Wo        = (const float*)d_in[9];
  const float* sshift    = (const float*)d_in[10];
  float* out = (float*)d_out;

  char* ws = (char*)d_ws;
  size_t off = 0;
  auto alloc = [&](size_t bytes) { char* p = ws + off; off += (bytes + 255) & ~(size_t)255; return p; };
  unsigned short* hidden_bf = (unsigned short*)alloc((size_t)QLEN * HID * 2);
  unsigned short* wbuf      = (unsigned short*)alloc((size_t)HID * HID * 2);
  unsigned short* qbf       = (unsigned short*)alloc((size_t)NH * QLEN * HD * 2);
  unsigned short* kallp     = (unsigned short*)alloc((size_t)NH * KVLEN * HD * 2);
  unsigned short* vallT     = (unsigned short*)alloc((size_t)NH * HD * KVLEN * 2);
  unsigned short* ctx       = (unsigned short*)alloc((size_t)QLEN * HID * 2);
  float2*         cs2       = (float2*)alloc((size_t)QLEN * 64 * 8);
  float*          part      = (float*)alloc((size_t)16 * HID * 4);
  float*          hsum      = (float*)alloc(HID * 4);
  float*          qs        = (float*)alloc(HID * 4);
  float*          scores    = (float*)alloc(KBLEN * 4);
  int*            idx       = (int*)alloc(NTOPK * 4);

  // d_out (33.55MB fp32 = exactly HID*HID bf16) is dead until the final
  // out-projection, which overwrites every element -> use as Wk-bf16 scratch.
  unsigned short* wkbuf = (unsigned short*)out;

  dim3 blk(256);

  k_cast<<<QLEN * HID / 4 / 256, blk, 0, stream>>>(hidden, hidden_bf, QLEN * HID / 4);
  k_rowsum_p<<<dim3(HID / 256, 16), blk, 0, stream>>>(hidden, part);
  k_rowsum_r<<<HID / 256, blk, 0, stream>>>(part, hsum);
  k_dotrows<<<HID / 4, blk, 0, stream>>>(hsum, Wq2, qs, HID, 1.0f);
  k_dotrows<<<KBLEN / 4, blk, 0, stream>>>(qs, kb_keys, scores, HID, SCALE);
  k_topk<<<1, KBLEN, 0, stream>>>(scores, idx);
  k_cs<<<QLEN * 64 / 256, blk, 0, stream>>>(pos, cs2);

  dim3 ggrid(HID / 256, QLEN / 128);  // (16, 16) = 256 blocks
  dim3 gblk(512);
  int wcast_blocks = HID * HID / 4 / 256;

  // merged Wq+Wk cast, then merged Q+K projection+RoPE (512 blocks)
  k_cast2<<<2 * wcast_blocks, blk, 0, stream>>>(Wq, Wk, wbuf, wkbuf, HID * HID / 4);
  dim3 qkgrid(16, 32);
  gemm_qk<<<qkgrid, gblk, 0, stream>>>(hidden_bf, wbuf, wkbuf, qbf, kallp, cs2);

  // V projection -> v_all^T[h][d][128+q]
  k_cast<<<wcast_blocks, blk, 0, stream>>>(Wv, wbuf, HID * HID / 4);
  gemm_bt<3><<<ggrid, gblk, 0, stream>>>(hidden_bf, wbuf, nullptr, vallT, QLEN, HID, HID, KVLEN, NTOPK, cs2, 1.0f);

  // gather selected KB keys/values into k_all[:, :128] / v_all^T[:, :, :128]
  k_gather<<<NH * NTOPK * HD / 256, blk, 0, stream>>>(kb_keys, kb_values, idx, kallp, vallT);

  // flash attention -> ctx bf16 [q][h*128+d]
  dim3 agrid(32, NH);   // 1024 single-chunk blocks
  attn_kernel<<<agrid, blk, 0, stream>>>(qbf, kallp, vallT, sshift, ctx);

  // output projection -> d_out fp32 (overwrites the wkbuf scratch fully)
  k_cast<<<wcast_blocks, blk, 0, stream>>>(Wo, wbuf, HID * HID / 4);
  gemm_bt<0><<<ggrid, gblk, 0, stream>>>(ctx, wbuf, out, nullptr, QLEN, HID, HID, 0, 0, cs2, 1.0f);
}

// Round 16
// 554.123 us; speedup vs baseline: 1.7679x; 1.0136x over previous
//
#include <hip/hip_runtime.h>
#include <stdint.h>
#include <stddef.h>

#define NH 32
#define HD 128
#define HID 4096
#define QLEN 2048
#define KBLEN 1024
#define NTOPK 128
#define KVLEN 2176   // NTOPK + QLEN
#define PADV -1e9f
#define SCALE 0.08838834764831845f
#define LOG2E 1.4426950408889634f
#define SC2 (SCALE * LOG2E)          // score scale in log2 domain (folded into Q)
#define DEFER_THR 8.0f

typedef __attribute__((ext_vector_type(4))) float f32x4;
typedef __attribute__((ext_vector_type(4))) unsigned short u16x4;
typedef __attribute__((ext_vector_type(8))) short s16x8;

typedef const __attribute__((address_space(1))) void* gas1_t;
typedef __attribute__((address_space(3))) void* las3_t;

__device__ __forceinline__ void gload_lds16(const void* g, void* l) {
  __builtin_amdgcn_global_load_lds((gas1_t)g, (las3_t)l, 16, 0, 0);
}

__device__ __forceinline__ unsigned short f2bf(float x) {
  union { float f; unsigned u; } z; z.f = x;
  unsigned r = z.u + 0x7fffu + ((z.u >> 16) & 1u);
  return (unsigned short)(r >> 16);
}

// ---------------- small prep kernels ----------------

__global__ void k_cast(const float* __restrict__ src, unsigned short* __restrict__ dst, int n4) {
  int i = blockIdx.x * 256 + threadIdx.x;
  if (i >= n4) return;
  f32x4 v = ((const f32x4*)src)[i];
  u16x4 o;
  o[0] = f2bf(v[0]); o[1] = f2bf(v[1]); o[2] = f2bf(v[2]); o[3] = f2bf(v[3]);
  ((u16x4*)dst)[i] = o;
}

// quad cast: four weights in one launch (grid = 4*n4each/256 blocks)
__global__ void k_cast4(const float* __restrict__ s0, const float* __restrict__ s1,
                        const float* __restrict__ s2, const float* __restrict__ s3,
                        unsigned short* __restrict__ d0, unsigned short* __restrict__ d1,
                        unsigned short* __restrict__ d2, unsigned short* __restrict__ d3,
                        int n4each) {
  int i = blockIdx.x * 256 + threadIdx.x;
  int grp = i / n4each;
  int j = i - grp * n4each;
  const float* s = (grp == 0) ? s0 : (grp == 1) ? s1 : (grp == 2) ? s2 : s3;
  unsigned short* d = (grp == 0) ? d0 : (grp == 1) ? d1 : (grp == 2) ? d2 : d3;
  f32x4 v = ((const f32x4*)s)[j];
  u16x4 o;
  o[0] = f2bf(v[0]); o[1] = f2bf(v[1]); o[2] = f2bf(v[2]); o[3] = f2bf(v[3]);
  ((u16x4*)d)[j] = o;
}

// column sums of hidden: two-stage, deterministic (no atomics -> top-k stable)
__global__ void k_rowsum_p(const float* __restrict__ x, float* __restrict__ part) {
  int d = blockIdx.x * 256 + threadIdx.x;
  int q0 = blockIdx.y * 128;
  float acc = 0.f;
  for (int q = q0; q < q0 + 128; ++q) acc += x[(size_t)q * HID + d];
  part[(size_t)blockIdx.y * HID + d] = acc;
}
__global__ void k_rowsum_r(const float* __restrict__ part, float* __restrict__ out) {
  int d = blockIdx.x * 256 + threadIdx.x;
  float acc = 0.f;
#pragma unroll
  for (int i = 0; i < 16; ++i) acc += part[(size_t)i * HID + d];
  out[d] = acc;
}

// out[n] = s * dot(vec, mat[n,:]) ; one wave per n, 4 waves/block
__global__ void k_dotrows(const float* __restrict__ vec, const float* __restrict__ mat,
                          float* __restrict__ out, int K, float s) {
  int n = blockIdx.x * 4 + (threadIdx.x >> 6);
  int lane = threadIdx.x & 63;
  const float* row = mat + (size_t)n * K;
  float acc = 0.f;
  for (int j = lane; j < K; j += 64) acc += vec[j] * row[j];
#pragma unroll
  for (int off = 32; off > 0; off >>= 1) acc += __shfl_down(acc, off, 64);
  if (lane == 0) out[n] = acc * s;
}

// stable top-k by rank counting (tie-break: lower index wins, matches lax.top_k)
__global__ void k_topk(const float* __restrict__ scores, int* __restrict__ idx) {
  __shared__ float s[KBLEN];
  int t = threadIdx.x;
  s[t] = scores[t];
  __syncthreads();
  float mine = s[t];
  int rank = 0;
  for (int j = 0; j < KBLEN; ++j) {
    float v = s[j];
    rank += (v > mine) || (v == mine && j < t);
  }
  if (rank < NTOPK) idx[rank] = t;
}

// cos/sin table, interleaved pairs: cs[p*64+i] = {cos, sin} of pos_p * invf_i
__global__ void k_cs(const int* __restrict__ pos_ids, float2* __restrict__ cs) {
  int t = blockIdx.x * 256 + threadIdx.x;   // QLEN*64 threads
  int p = t >> 6, i = t & 63;
  float pos = (float)pos_ids[p];
  float invf = powf(10000.0f, -(float)i / 64.0f);
  float a = pos * invf;
  cs[p * 64 + i] = make_float2(cosf(a), sinf(a));
}

// gather selected KB rows: K -> kall[h][i][d], V -> vallT[h][d][i] (transposed)
__global__ void k_gather(const float* __restrict__ kbk, const float* __restrict__ kbv,
                         const int* __restrict__ idx,
                         unsigned short* __restrict__ kall, unsigned short* __restrict__ vallT) {
  int t = blockIdx.x * 256 + threadIdx.x;   // NH*NTOPK*HD threads
  int d = t & 127;
  int i = (t >> 7) & 127;
  int hh = t >> 14;
  int kr = idx[i];
  size_t src = (size_t)kr * HID + hh * HD + d;
  kall[((size_t)hh * KVLEN + i) * HD + d] = f2bf(kbk[src]);
  vallT[((size_t)hh * HD + d) * KVLEN + i] = f2bf(kbv[src]);
}

// ---------------- bf16 MFMA GEMM: C[m,n] = sum_k A[m,k]*B[n,k] ----------------
// Pipelined template (T1+T2+T3+T4+T5): BM=128, BN=256, BK=64, 512 threads =
// 8 waves (2M x 4N), per-wave 64x64 output. 3 LDS buffers, ONE raw s_barrier
// + ONE counted vmcnt(6) per K-tile. Wave's 4 column groups remapped to
// {d, d+16, d+64, d+80} within one head (rotate-half pairs register-local).
#define GBK 64
#define ABUF 8192    // elems per buffer for A (128x64)
#define BBUF 16384   // elems per buffer for B (256x64)
#define BUFE (ABUF + BBUF)

#define GEMM_MAIN_LOOP                                                         \
  f32x4 acc[4][4] = {};                                                        \
  stageA(0, 0, 0); stageA(0, 0, 1);                                            \
  stageB(0, 0, 0); stageB(0, 0, 1); stageB(0, 0, 2); stageB(0, 0, 3);          \
  stageA(1, BUFE, 0); stageA(1, BUFE, 1);                                      \
  stageB(1, BUFE, 0); stageB(1, BUFE, 1); stageB(1, BUFE, 2); stageB(1, BUFE, 3); \
  const int NT = K / GBK;                                                      \
  const int sa = (lo & 7) << 3;                                                \
  const int bbase = (wn >> 1) * 128 + (wn & 1) * 32;                           \
  int bi = 0;                                                                  \
  for (int kt = 0; kt < NT; ++kt) {                                            \
    if (kt < NT - 1) { asm volatile("s_waitcnt vmcnt(6)" ::: "memory"); }      \
    else             { asm volatile("s_waitcnt vmcnt(0)" ::: "memory"); }      \
    __builtin_amdgcn_sched_barrier(0);                                         \
    __builtin_amdgcn_s_barrier();                                              \
    __builtin_amdgcn_sched_barrier(0);                                         \
    const int bufe = bi * BUFE;                                                \
    const int nbufe = ((bi + 2 >= 3) ? bi - 1 : bi + 2) * BUFE;                \
    const bool pre = (kt + 2 < NT);                                            \
    const unsigned short* Ab = lds + bufe;                                     \
    const unsigned short* Bb = lds + bufe + ABUF;                              \
    const int arow = wm * 64 + lo;                                             \
    const int brow = bbase + lo;                                               \
    s16x8 af[4], b01[2], b23[2];                                               \
    const int c0 = (hi * 8) ^ sa;                                              \
    const int c1 = (32 + hi * 8) ^ sa;                                         \
    _Pragma("unroll")                                                          \
    for (int i = 0; i < 4; ++i) af[i] = *(const s16x8*)(Ab + (arow + i * 16) * 64 + c0); \
    b01[0] = *(const s16x8*)(Bb + (brow +  0) * 64 + c0);                      \
    b01[1] = *(const s16x8*)(Bb + (brow + 16) * 64 + c0);                      \
    if (pre) { stageA(kt + 2, nbufe, 0); stageA(kt + 2, nbufe, 1); }           \
    asm volatile("s_waitcnt lgkmcnt(0)" ::: "memory");                         \
    __builtin_amdgcn_sched_barrier(0);                                         \
    __builtin_amdgcn_s_setprio(1);                                             \
    _Pragma("unroll")                                                          \
    for (int i = 0; i < 4; ++i) {                                              \
      acc[i][0] = __builtin_amdgcn_mfma_f32_16x16x32_bf16(af[i], b01[0], acc[i][0], 0, 0, 0); \
      acc[i][1] = __builtin_amdgcn_mfma_f32_16x16x32_bf16(af[i], b01[1], acc[i][1], 0, 0, 0); \
    }                                                                          \
    __builtin_amdgcn_s_setprio(0);                                             \
    b23[0] = *(const s16x8*)(Bb + (brow + 64) * 64 + c0);                      \
    b23[1] = *(const s16x8*)(Bb + (brow + 80) * 64 + c0);                      \
    if (pre) { stageB(kt + 2, nbufe, 0); stageB(kt + 2, nbufe, 1); }           \
    asm volatile("s_waitcnt lgkmcnt(0)" ::: "memory");                         \
    __builtin_amdgcn_sched_barrier(0);                                         \
    __builtin_amdgcn_s_setprio(1);                                             \
    _Pragma("unroll")                                                          \
    for (int i = 0; i < 4; ++i) {                                              \
      acc[i][2] = __builtin_amdgcn_mfma_f32_16x16x32_bf16(af[i], b23[0], acc[i][2], 0, 0, 0); \
      acc[i][3] = __builtin_amdgcn_mfma_f32_16x16x32_bf16(af[i], b23[1], acc[i][3], 0, 0, 0); \
    }                                                                          \
    __builtin_amdgcn_s_setprio(0);                                             \
    _Pragma("unroll")                                                          \
    for (int i = 0; i < 4; ++i) af[i] = *(const s16x8*)(Ab + (arow + i * 16) * 64 + c1); \
    b01[0] = *(const s16x8*)(Bb + (brow +  0) * 64 + c1);                      \
    b01[1] = *(const s16x8*)(Bb + (brow + 16) * 64 + c1);                      \
    if (pre) { stageB(kt + 2, nbufe, 2); stageB(kt + 2, nbufe, 3); }           \
    asm volatile("s_waitcnt lgkmcnt(0)" ::: "memory");                         \
    __builtin_amdgcn_sched_barrier(0);                                         \
    __builtin_amdgcn_s_setprio(1);                                             \
    _Pragma("unroll")                                                          \
    for (int i = 0; i < 4; ++i) {                                              \
      acc[i][0] = __builtin_amdgcn_mfma_f32_16x16x32_bf16(af[i], b01[0], acc[i][0], 0, 0, 0); \
      acc[i][1] = __builtin_amdgcn_mfma_f32_16x16x32_bf16(af[i], b01[1], acc[i][1], 0, 0, 0); \
    }                                                                          \
    __builtin_amdgcn_s_setprio(0);                                             \
    b23[0] = *(const s16x8*)(Bb + (brow + 64) * 64 + c1);                      \
    b23[1] = *(const s16x8*)(Bb + (brow + 80) * 64 + c1);                      \
    asm volatile("s_waitcnt lgkmcnt(0)" ::: "memory");                         \
    __builtin_amdgcn_sched_barrier(0);                                         \
    __builtin_amdgcn_s_setprio(1);                                             \
    _Pragma("unroll")                                                          \
    for (int i = 0; i < 4; ++i) {                                              \
      acc[i][2] = __builtin_amdgcn_mfma_f32_16x16x32_bf16(af[i], b23[0], acc[i][2], 0, 0, 0); \
      acc[i][3] = __builtin_amdgcn_mfma_f32_16x16x32_bf16(af[i], b23[1], acc[i][3], 0, 0, 0); \
    }                                                                          \
    __builtin_amdgcn_s_setprio(0);                                             \
    bi = (bi + 1 == 3) ? 0 : bi + 1;                                           \
  }

// generic single-tensor GEMM (MODE 0 = fp32 row-major; used for out-proj)
template<int MODE>
__global__ __launch_bounds__(512)
void gemm_bt(const unsigned short* __restrict__ A, const unsigned short* __restrict__ B,
             float* __restrict__ Cf, unsigned short* __restrict__ Cb,
             int M, int N, int K, int RH, int RO, const float2* __restrict__ cs2,
             float qsc) {
  __shared__ unsigned short lds[3 * BUFE];   // 144 KiB
  const int tid = threadIdx.x;
  const int lane = tid & 63;
  const int wave = tid >> 6;
  const int lo = lane & 15, hi = lane >> 4;
  const int wm = wave >> 2, wn = wave & 3;

  const int nwg = gridDim.x * gridDim.y;
  const int orig = blockIdx.y * gridDim.x + blockIdx.x;
  const int wg = (orig & 7) * (nwg >> 3) + (orig >> 3);
  const int bx = wg % gridDim.x, by = wg / gridDim.x;
  const int m0 = by * 128, n0 = bx * 256;

  auto stageA = [&](int kt, int bufe, int g) {
    int j0 = g * 512 + wave * 64;
    int j = j0 + lane;
    int row = j >> 3, cb = j & 7;
    gload_lds16(A + (size_t)(m0 + row) * K + kt * GBK + ((cb ^ (row & 7)) << 3),
                (void*)(lds + bufe + j0 * 8));
  };
  auto stageB = [&](int kt, int bufe, int g) {
    int j0 = g * 512 + wave * 64;
    int j = j0 + lane;
    int row = j >> 3, cb = j & 7;
    gload_lds16(B + (size_t)(n0 + row) * K + kt * GBK + ((cb ^ (row & 7)) << 3),
                (void*)(lds + bufe + ABUF + j0 * 8));
  };

  GEMM_MAIN_LOOP

#pragma unroll
  for (int i = 0; i < 4; ++i) {
#pragma unroll
    for (int j = 0; j < 4; ++j) {
#pragma unroll
      for (int r = 0; r < 4; ++r) {
        int row = m0 + wm * 64 + i * 16 + hi * 4 + r;   // C/D: row=(l>>4)*4+reg
        int col = n0 + bbase + (j >> 1) * 64 + (j & 1) * 16 + lo;
        float v = acc[i][j][r];
        if (MODE == 0) {
          Cf[(size_t)row * N + col] = v;
        } else {
          int hh = col >> 7, d = col & 127;
          Cb[((size_t)hh * RH + RO + row) * HD + d] = f2bf(v);
        }
      }
    }
  }
}

// Merged Q+K+V projection: 768 blocks; after bijective XCD swizzle,
// grp = wg/256 selects {Q: RoPE+SC2 -> qbf, K: RoPE -> kallp, V: transposed
// -> vallT}. Body identical to gemm_bt; epilogue branches are wave-uniform.
__global__ __launch_bounds__(512)
void gemm_qkv(const unsigned short* __restrict__ A,
              const unsigned short* __restrict__ B0, const unsigned short* __restrict__ B1,
              const unsigned short* __restrict__ B2,
              unsigned short* __restrict__ C0, unsigned short* __restrict__ C1,
              unsigned short* __restrict__ C2,
              const float2* __restrict__ cs2) {
  __shared__ unsigned short lds[3 * BUFE];   // 144 KiB
  const int tid = threadIdx.x;
  const int lane = tid & 63;
  const int wave = tid >> 6;
  const int lo = lane & 15, hi = lane >> 4;
  const int wm = wave >> 2, wn = wave & 3;

  const int nwg = gridDim.x * gridDim.y;                 // 768
  const int orig = blockIdx.y * gridDim.x + blockIdx.x;
  const int wg = (orig & 7) * (nwg >> 3) + (orig >> 3);
  const int grp = wg >> 8;                               // 0=Q 1=K 2=V
  const int rem = wg & 255;
  const int bx = rem & 15, by = rem >> 4;
  const int m0 = by * 128, n0 = bx * 256;

  const unsigned short* B = (grp == 0) ? B0 : (grp == 1) ? B1 : B2;
  const int K = HID;

  auto stageA = [&](int kt, int bufe, int g) {
    int j0 = g * 512 + wave * 64;
    int j = j0 + lane;
    int row = j >> 3, cb = j & 7;
    gload_lds16(A + (size_t)(m0 + row) * K + kt * GBK + ((cb ^ (row & 7)) << 3),
                (void*)(lds + bufe + j0 * 8));
  };
  auto stageB = [&](int kt, int bufe, int g) {
    int j0 = g * 512 + wave * 64;
    int j = j0 + lane;
    int row = j >> 3, cb = j & 7;
    gload_lds16(B + (size_t)(n0 + row) * K + kt * GBK + ((cb ^ (row & 7)) << 3),
                (void*)(lds + bufe + ABUF + j0 * 8));
  };

  GEMM_MAIN_LOOP

  if (grp < 2) {
    // RoPE epilogue (Q: qsc=SC2, dst qbf/QLEN/0; K: qsc=1, dst kallp/KVLEN/NTOPK)
    unsigned short* Cb = grp ? C1 : C0;
    const float qsc = grp ? 1.0f : (float)SC2;
    const int RH = grp ? KVLEN : QLEN;
    const int RO = grp ? NTOPK : 0;
#pragma unroll
    for (int i = 0; i < 4; ++i) {
#pragma unroll
      for (int j = 0; j < 2; ++j) {
#pragma unroll
        for (int r = 0; r < 4; ++r) {
          int row = m0 + wm * 64 + i * 16 + hi * 4 + r;
          int col = n0 + bbase + j * 16 + lo;
          int hh = col >> 7, d = col & 127;          // d in [0,64)
          float2 cp = cs2[row * 64 + d];
          float x1 = acc[i][j][r] * qsc, x2 = acc[i][j + 2][r] * qsc;
          size_t base = ((size_t)hh * RH + RO + row) * HD;
          Cb[base + d]      = f2bf(x1 * cp.x - x2 * cp.y);
          Cb[base + d + 64] = f2bf(x2 * cp.x + x1 * cp.y);
        }
      }
    }
  } else {
    // V: transposed store vallT[h][d][NTOPK + kv], 4 consecutive kv per reg quad
#pragma unroll
    for (int i = 0; i < 4; ++i) {
#pragma unroll
      for (int j = 0; j < 4; ++j) {
        int rowb = m0 + wm * 64 + i * 16 + hi * 4;
        int col = n0 + bbase + (j >> 1) * 64 + (j & 1) * 16 + lo;
        int hh = col >> 7, d = col & 127;
        u16x4 o4;
#pragma unroll
        for (int r = 0; r < 4; ++r) o4[r] = f2bf(acc[i][j][r]);
        *(u16x4*)(C2 + ((size_t)hh * HD + d) * KVLEN + NTOPK + rowb) = o4;
      }
    }
  }
}

// ---------------- flash attention (R7 structure: best measured) ----------------
__global__ __launch_bounds__(256)
void attn_kernel(const unsigned short* __restrict__ qh,
                 const unsigned short* __restrict__ kall,
                 const unsigned short* __restrict__ vallT,
                 const float* __restrict__ sshift,
                 unsigned short* __restrict__ ctx) {
  __shared__ __align__(1024) unsigned short Ks[64 * 128];
  __shared__ __align__(1024) unsigned short Vs[128 * 64];
  __shared__ __align__(16)  unsigned short Plds[4][16 * 72];

  int orig = blockIdx.y * 32 + blockIdx.x;
  int wgid = (orig & 7) * 128 + (orig >> 3);   // bijective XCD swizzle (1024 = 8*128)
  int h = wgid >> 5;
  int qc = 31 - (wgid & 31);                   // heaviest chunks launch first

  const int tid = threadIdx.x;
  const int lane = tid & 63;
  const int wave = tid >> 6;
  const int lo = lane & 15;
  const int hi = lane >> 4;
  const float shiftL = sshift[h] * LOG2E;

  const unsigned short* kb = kall + (size_t)h * KVLEN * HD;
  const unsigned short* vtb = vallT + (size_t)h * HD * KVLEN;

  const int m0 = qc * 64;
  const int nt = qc + 3;
  const int qrow = m0 + wave * 16 + hi * 4;

  s16x8 qf[4];
  {
    const unsigned short* qp = qh + ((size_t)h * QLEN + m0 + wave * 16 + lo) * HD + hi * 8;
#pragma unroll
    for (int kc = 0; kc < 4; ++kc) qf[kc] = *(const s16x8*)(qp + kc * 32);
  }

  float m_run[4], l_part[4];
#pragma unroll
  for (int r = 0; r < 4; ++r) { m_run[r] = -1e30f; l_part[r] = 0.f; }
  f32x4 o[8] = {};

  for (int kt = 0; kt < nt; ++kt) {
    const unsigned short* kg = kb + (size_t)kt * 64 * HD;
    const unsigned short* vg = vtb + kt * 64;
    __syncthreads();   // prior tile's readers done before overwrite
#pragma unroll
    for (int it = 0; it < 4; ++it) {
      int j0 = it * 256 + wave * 64;
      int j = j0 + lane;
      int row = j >> 4, cb = j & 15;
      gload_lds16(kg + row * 128 + ((cb ^ (row & 7)) * 8), (void*)(Ks + j0 * 8));
      int d = j >> 3, c = j & 7;
      gload_lds16(vg + (size_t)d * KVLEN + ((c ^ (d & 7)) << 3), (void*)(Vs + j0 * 8));
    }
    __syncthreads();   // implicit vmcnt(0): tile staged & visible

    // S = Q K^T : 16 q-rows x 64 keys per wave (Q pre-scaled by SC2)
    f32x4 s[4] = {};
#pragma unroll
    for (int kc = 0; kc < 4; ++kc) {
#pragma unroll
      for (int g = 0; g < 4; ++g) {
        int key = g * 16 + lo;
        s16x8 kf = *(const s16x8*)(Ks + key * 128 + (((kc * 4 + hi) ^ (key & 7)) * 8));
        s[g] = __builtin_amdgcn_mfma_f32_16x16x32_bf16(qf[kc], kf, s[g], 0, 0, 0);
      }
    }

    // tile-type adjustment (uniform branches)
    if (kt < 2) {
#pragma unroll
      for (int g = 0; g < 4; ++g)
#pragma unroll
        for (int r = 0; r < 4; ++r) s[g][r] += shiftL;
    } else if (kt == nt - 1) {
      const int kvbase = kt * 64;
#pragma unroll
      for (int r = 0; r < 4; ++r) {
        int qr = qrow + r;
#pragma unroll
        for (int g = 0; g < 4; ++g) {
          int kv = kvbase + g * 16 + lo;
          s[g][r] = (kv - NTOPK > qr) ? PADV : s[g][r];
        }
      }
    }

    // vote-based defer-max
    float mx[4];
    bool need = false;
#pragma unroll
    for (int r = 0; r < 4; ++r) {
      mx[r] = fmaxf(fmaxf(s[0][r], s[1][r]), fmaxf(s[2][r], s[3][r]));
      need = need || (mx[r] > m_run[r] + DEFER_THR);
    }
    if (__any((int)need)) {
#pragma unroll
      for (int off = 1; off < 16; off <<= 1)
#pragma unroll
        for (int r = 0; r < 4; ++r) mx[r] = fmaxf(mx[r], __shfl_xor(mx[r], off, 64));
#pragma unroll
      for (int r = 0; r < 4; ++r) {
        float mn = fmaxf(m_run[r], mx[r]);
        float alpha = __builtin_amdgcn_exp2f(m_run[r] - mn);
        m_run[r] = mn;
        l_part[r] *= alpha;
#pragma unroll
        for (int db = 0; db < 8; ++db) o[db][r] *= alpha;
      }
    }

    // p = exp2(s - m), lane-partial l, P -> LDS
#pragma unroll
    for (int r = 0; r < 4; ++r) {
#pragma unroll
      for (int g = 0; g < 4; ++g) {
        float p = __builtin_amdgcn_exp2f(s[g][r] - m_run[r]);
        l_part[r] += p;
        Plds[wave][(hi * 4 + r) * 72 + g * 16 + lo] = f2bf(p);
      }
    }

    // PV: A = P (same-wave LDS round trip), B = V^T single b128 per frag
    s16x8 pf0 = *(const s16x8*)(&Plds[wave][lo * 72 + hi * 8]);
    s16x8 pf1 = *(const s16x8*)(&Plds[wave][lo * 72 + 32 + hi * 8]);
#pragma unroll
    for (int db = 0; db < 8; ++db) {
      int d = db * 16 + lo;
      s16x8 vf0 = *(const s16x8*)(Vs + d * 64 + ((hi       ^ (d & 7)) << 3));
      s16x8 vf1 = *(const s16x8*)(Vs + d * 64 + (((4 + hi) ^ (d & 7)) << 3));
      o[db] = __builtin_amdgcn_mfma_f32_16x16x32_bf16(pf0, vf0, o[db], 0, 0, 0);
      o[db] = __builtin_amdgcn_mfma_f32_16x16x32_bf16(pf1, vf1, o[db], 0, 0, 0);
    }
  } // kt

  // reduce lane-partial l across the 16 lo lanes (once per block)
#pragma unroll
  for (int off = 1; off < 16; off <<= 1)
#pragma unroll
    for (int r = 0; r < 4; ++r) l_part[r] += __shfl_xor(l_part[r], off, 64);

  float rinv[4];
#pragma unroll
  for (int r = 0; r < 4; ++r) rinv[r] = __builtin_amdgcn_rcpf(l_part[r]);

  // normalize + write ctx[q][h*128+d] bf16
#pragma unroll
  for (int db = 0; db < 8; ++db) {
#pragma unroll
    for (int r = 0; r < 4; ++r) {
      int row = qrow + r;
      int col = h * HD + db * 16 + lo;
      ctx[(size_t)row * HID + col] = f2bf(o[db][r] * rinv[r]);
    }
  }
}

// ---------------- launch ----------------

extern "C" void kernel_launch(void* const* d_in, const int* in_sizes, int n_in,
                              void* d_out, int out_size, void* d_ws, size_t ws_size,
                              hipStream_t stream) {
  const float* hidden    = (const float*)d_in[0];
  const int*   pos       = (const int*)d_in[2];
  const float* kb_keys   = (const float*)d_in[3];
  const float* kb_values = (const float*)d_in[4];
  const float* Wq        = (const float*)d_in[5];
  const float* Wq2       = (const float*)d_in[6];
  const float* Wk        = (const float*)d_in[7];
  const float* Wv        = (const float*)d_in[8];
  const float* Wo        = (const float*)d_in[9];
  const float* sshift    = (const float*)d_in[10];
  float* out = (float*)d_out;

  char* ws = (char*)d_ws;
  size_t off = 0;
  auto alloc = [&](size_t bytes) { char* p = ws + off; off += (bytes + 255) & ~(size_t)255; return p; };
  unsigned short* hidden_bf = (unsigned short*)alloc((size_t)QLEN * HID * 2);
  unsigned short* wbuf      = (unsigned short*)alloc((size_t)HID * HID * 2);   // Wq bf16
  unsigned short* wvbuf     = (unsigned short*)alloc((size_t)HID * HID * 2);   // Wv bf16
  unsigned short* wobuf     = (unsigned short*)alloc((size_t)HID * HID * 2);   // Wo bf16
  unsigned short* qbf       = (unsigned short*)alloc((size_t)NH * QLEN * HD * 2);
  unsigned short* kallp     = (unsigned short*)alloc((size_t)NH * KVLEN * HD * 2);
  unsigned short* vallT     = (unsigned short*)alloc((size_t)NH * HD * KVLEN * 2);
  unsigned short* ctx       = (unsigned short*)alloc((size_t)QLEN * HID * 2);
  float2*         cs2       = (float2*)alloc((size_t)QLEN * 64 * 8);
  float*          part      = (float*)alloc((size_t)16 * HID * 4);
  float*          hsum      = (float*)alloc(HID * 4);
  float*          qs        = (float*)alloc(HID * 4);
  float*          scores    = (float*)alloc(KBLEN * 4);
  int*            idx       = (int*)alloc(NTOPK * 4);

  // d_out (33.55MB fp32 = exactly HID*HID bf16) is dead until the final
  // out-projection, which overwrites every element -> use as Wk-bf16 scratch.
  unsigned short* wkbuf = (unsigned short*)out;

  dim3 blk(256);
  int wcast_blocks = HID * HID / 4 / 256;

  k_cast<<<QLEN * HID / 4 / 256, blk, 0, stream>>>(hidden, hidden_bf, QLEN * HID / 4);
  k_rowsum_p<<<dim3(HID / 256, 16), blk, 0, stream>>>(hidden, part);
  k_rowsum_r<<<HID / 256, blk, 0, stream>>>(part, hsum);
  k_dotrows<<<HID / 4, blk, 0, stream>>>(hsum, Wq2, qs, HID, 1.0f);
  k_dotrows<<<KBLEN / 4, blk, 0, stream>>>(qs, kb_keys, scores, HID, SCALE);
  k_topk<<<1, KBLEN, 0, stream>>>(scores, idx);
  k_cs<<<QLEN * 64 / 256, blk, 0, stream>>>(pos, cs2);

  // all four weight casts in one launch
  k_cast4<<<4 * wcast_blocks, blk, 0, stream>>>(Wq, Wk, Wv, Wo,
                                                wbuf, wkbuf, wvbuf, wobuf,
                                                HID * HID / 4);

  // merged Q+K+V projection (+RoPE, +V-transpose) -- 768 blocks
  dim3 gblk(512);
  dim3 qkvgrid(16, 48);
  gemm_qkv<<<qkvgrid, gblk, 0, stream>>>(hidden_bf, wbuf, wkbuf, wvbuf,
                                         qbf, kallp, vallT, cs2);

  // gather selected KB keys/values into k_all[:, :128] / v_all^T[:, :, :128]
  k_gather<<<NH * NTOPK * HD / 256, blk, 0, stream>>>(kb_keys, kb_values, idx, kallp, vallT);

  // flash attention -> ctx bf16 [q][h*128+d]
  dim3 agrid(32, NH);   // 1024 single-chunk blocks
  attn_kernel<<<agrid, blk, 0, stream>>>(qbf, kallp, vallT, sshift, ctx);

  // output projection -> d_out fp32 (overwrites the wkbuf scratch fully)
  dim3 ggrid(HID / 256, QLEN / 128);  // 256 blocks
  gemm_bt<0><<<ggrid, gblk, 0, stream>>>(ctx, wobuf, out, nullptr, QLEN, HID, HID, 0, 0, cs2, 1.0f);
}

// Round 17
// 548.216 us; speedup vs baseline: 1.7869x; 1.0108x over previous
//
#include <hip/hip_runtime.h>
#include <stdint.h>
#include <stddef.h>

#define NH 32
#define HD 128
#define HID 4096
#define QLEN 2048
#define KBLEN 1024
#define NTOPK 128
#define KVLEN 2176   // NTOPK + QLEN
#define PADV -1e9f
#define SCALE 0.08838834764831845f
#define LOG2E 1.4426950408889634f
#define SC2 (SCALE * LOG2E)          // score scale in log2 domain (folded into Q)
#define DEFER_THR 8.0f

typedef __attribute__((ext_vector_type(4))) float f32x4;
typedef __attribute__((ext_vector_type(4))) unsigned short u16x4;
typedef __attribute__((ext_vector_type(8))) short s16x8;

typedef const __attribute__((address_space(1))) void* gas1_t;
typedef __attribute__((address_space(3))) void* las3_t;

__device__ __forceinline__ void gload_lds16(const void* g, void* l) {
  __builtin_amdgcn_global_load_lds((gas1_t)g, (las3_t)l, 16, 0, 0);
}

__device__ __forceinline__ unsigned short f2bf(float x) {
  union { float f; unsigned u; } z; z.f = x;
  unsigned r = z.u + 0x7fffu + ((z.u >> 16) & 1u);
  return (unsigned short)(r >> 16);
}

// ---------------- small prep kernels ----------------

__global__ void k_cast(const float* __restrict__ src, unsigned short* __restrict__ dst, int n4) {
  int i = blockIdx.x * 256 + threadIdx.x;
  if (i >= n4) return;
  f32x4 v = ((const f32x4*)src)[i];
  u16x4 o;
  o[0] = f2bf(v[0]); o[1] = f2bf(v[1]); o[2] = f2bf(v[2]); o[3] = f2bf(v[3]);
  ((u16x4*)dst)[i] = o;
}

// quad cast: four weights in one launch (grid = 4*n4each/256 blocks)
__global__ void k_cast4(const float* __restrict__ s0, const float* __restrict__ s1,
                        const float* __restrict__ s2, const float* __restrict__ s3,
                        unsigned short* __restrict__ d0, unsigned short* __restrict__ d1,
                        unsigned short* __restrict__ d2, unsigned short* __restrict__ d3,
                        int n4each) {
  int i = blockIdx.x * 256 + threadIdx.x;
  int grp = i / n4each;
  int j = i - grp * n4each;
  const float* s = (grp == 0) ? s0 : (grp == 1) ? s1 : (grp == 2) ? s2 : s3;
  unsigned short* d = (grp == 0) ? d0 : (grp == 1) ? d1 : (grp == 2) ? d2 : d3;
  f32x4 v = ((const f32x4*)s)[j];
  u16x4 o;
  o[0] = f2bf(v[0]); o[1] = f2bf(v[1]); o[2] = f2bf(v[2]); o[3] = f2bf(v[3]);
  ((u16x4*)d)[j] = o;
}

// column sums of hidden: two-stage, deterministic (no atomics -> top-k stable)
__global__ void k_rowsum_p(const float* __restrict__ x, float* __restrict__ part) {
  int d = blockIdx.x * 256 + threadIdx.x;
  int q0 = blockIdx.y * 128;
  float acc = 0.f;
  for (int q = q0; q < q0 + 128; ++q) acc += x[(size_t)q * HID + d];
  part[(size_t)blockIdx.y * HID + d] = acc;
}
__global__ void k_rowsum_r(const float* __restrict__ part, float* __restrict__ out) {
  int d = blockIdx.x * 256 + threadIdx.x;
  float acc = 0.f;
#pragma unroll
  for (int i = 0; i < 16; ++i) acc += part[(size_t)i * HID + d];
  out[d] = acc;
}

// out[n] = s * dot(vec, mat[n,:]) ; one wave per n, 4 waves/block
__global__ void k_dotrows(const float* __restrict__ vec, const float* __restrict__ mat,
                          float* __restrict__ out, int K, float s) {
  int n = blockIdx.x * 4 + (threadIdx.x >> 6);
  int lane = threadIdx.x & 63;
  const float* row = mat + (size_t)n * K;
  float acc = 0.f;
  for (int j = lane; j < K; j += 64) acc += vec[j] * row[j];
#pragma unroll
  for (int off = 32; off > 0; off >>= 1) acc += __shfl_down(acc, off, 64);
  if (lane == 0) out[n] = acc * s;
}

// stable top-k by rank counting (tie-break: lower index wins, matches lax.top_k)
__global__ void k_topk(const float* __restrict__ scores, int* __restrict__ idx) {
  __shared__ float s[KBLEN];
  int t = threadIdx.x;
  s[t] = scores[t];
  __syncthreads();
  float mine = s[t];
  int rank = 0;
  for (int j = 0; j < KBLEN; ++j) {
    float v = s[j];
    rank += (v > mine) || (v == mine && j < t);
  }
  if (rank < NTOPK) idx[rank] = t;
}

// cos/sin table, interleaved pairs: cs[p*64+i] = {cos, sin} of pos_p * invf_i
__global__ void k_cs(const int* __restrict__ pos_ids, float2* __restrict__ cs) {
  int t = blockIdx.x * 256 + threadIdx.x;   // QLEN*64 threads
  int p = t >> 6, i = t & 63;
  float pos = (float)pos_ids[p];
  float invf = powf(10000.0f, -(float)i / 64.0f);
  float a = pos * invf;
  cs[p * 64 + i] = make_float2(cosf(a), sinf(a));
}

// gather selected KB rows: K -> kall[h][i][d], V -> vallT[h][d][i] (transposed)
__global__ void k_gather(const float* __restrict__ kbk, const float* __restrict__ kbv,
                         const int* __restrict__ idx,
                         unsigned short* __restrict__ kall, unsigned short* __restrict__ vallT) {
  int t = blockIdx.x * 256 + threadIdx.x;   // NH*NTOPK*HD threads
  int d = t & 127;
  int i = (t >> 7) & 127;
  int hh = t >> 14;
  int kr = idx[i];
  size_t src = (size_t)kr * HID + hh * HD + d;
  kall[((size_t)hh * KVLEN + i) * HD + d] = f2bf(kbk[src]);
  vallT[((size_t)hh * HD + d) * KVLEN + i] = f2bf(kbv[src]);
}

// ---------------- bf16 MFMA GEMM: C[m,n] = sum_k A[m,k]*B[n,k] ----------------
// Pipelined template (T1+T2+T3+T4+T5): BM=128, BN=256, BK=64, 512 threads =
// 8 waves (2M x 4N), per-wave 64x64 output. 3 LDS buffers, ONE raw s_barrier
// + ONE counted vmcnt(6) per K-tile. Wave's 4 column groups remapped to
// {d, d+16, d+64, d+80} within one head (rotate-half pairs register-local).
#define GBK 64
#define ABUF 8192    // elems per buffer for A (128x64)
#define BBUF 16384   // elems per buffer for B (256x64)
#define BUFE (ABUF + BBUF)

#define GEMM_MAIN_LOOP                                                         \
  f32x4 acc[4][4] = {};                                                        \
  stageA(0, 0, 0); stageA(0, 0, 1);                                            \
  stageB(0, 0, 0); stageB(0, 0, 1); stageB(0, 0, 2); stageB(0, 0, 3);          \
  stageA(1, BUFE, 0); stageA(1, BUFE, 1);                                      \
  stageB(1, BUFE, 0); stageB(1, BUFE, 1); stageB(1, BUFE, 2); stageB(1, BUFE, 3); \
  const int NT = K / GBK;                                                      \
  const int sa = (lo & 7) << 3;                                                \
  const int bbase = (wn >> 1) * 128 + (wn & 1) * 32;                           \
  int bi = 0;                                                                  \
  for (int kt = 0; kt < NT; ++kt) {                                            \
    if (kt < NT - 1) { asm volatile("s_waitcnt vmcnt(6)" ::: "memory"); }      \
    else             { asm volatile("s_waitcnt vmcnt(0)" ::: "memory"); }      \
    __builtin_amdgcn_sched_barrier(0);                                         \
    __builtin_amdgcn_s_barrier();                                              \
    __builtin_amdgcn_sched_barrier(0);                                         \
    const int bufe = bi * BUFE;                                                \
    const int nbufe = ((bi + 2 >= 3) ? bi - 1 : bi + 2) * BUFE;                \
    const bool pre = (kt + 2 < NT);                                            \
    const unsigned short* Ab = lds + bufe;                                     \
    const unsigned short* Bb = lds + bufe + ABUF;                              \
    const int arow = wm * 64 + lo;                                             \
    const int brow = bbase + lo;                                               \
    s16x8 af[4], b01[2], b23[2];                                               \
    const int c0 = (hi * 8) ^ sa;                                              \
    const int c1 = (32 + hi * 8) ^ sa;                                         \
    _Pragma("unroll")                                                          \
    for (int i = 0; i < 4; ++i) af[i] = *(const s16x8*)(Ab + (arow + i * 16) * 64 + c0); \
    b01[0] = *(const s16x8*)(Bb + (brow +  0) * 64 + c0);                      \
    b01[1] = *(const s16x8*)(Bb + (brow + 16) * 64 + c0);                      \
    if (pre) { stageA(kt + 2, nbufe, 0); stageA(kt + 2, nbufe, 1); }           \
    asm volatile("s_waitcnt lgkmcnt(0)" ::: "memory");                         \
    __builtin_amdgcn_sched_barrier(0);                                         \
    __builtin_amdgcn_s_setprio(1);                                             \
    _Pragma("unroll")                                                          \
    for (int i = 0; i < 4; ++i) {                                              \
      acc[i][0] = __builtin_amdgcn_mfma_f32_16x16x32_bf16(af[i], b01[0], acc[i][0], 0, 0, 0); \
      acc[i][1] = __builtin_amdgcn_mfma_f32_16x16x32_bf16(af[i], b01[1], acc[i][1], 0, 0, 0); \
    }                                                                          \
    __builtin_amdgcn_s_setprio(0);                                             \
    b23[0] = *(const s16x8*)(Bb + (brow + 64) * 64 + c0);                      \
    b23[1] = *(const s16x8*)(Bb + (brow + 80) * 64 + c0);                      \
    if (pre) { stageB(kt + 2, nbufe, 0); stageB(kt + 2, nbufe, 1); }           \
    asm volatile("s_waitcnt lgkmcnt(0)" ::: "memory");                         \
    __builtin_amdgcn_sched_barrier(0);                                         \
    __builtin_amdgcn_s_setprio(1);                                             \
    _Pragma("unroll")                                                          \
    for (int i = 0; i < 4; ++i) {                                              \
      acc[i][2] = __builtin_amdgcn_mfma_f32_16x16x32_bf16(af[i], b23[0], acc[i][2], 0, 0, 0); \
      acc[i][3] = __builtin_amdgcn_mfma_f32_16x16x32_bf16(af[i], b23[1], acc[i][3], 0, 0, 0); \
    }                                                                          \
    __builtin_amdgcn_s_setprio(0);                                             \
    _Pragma("unroll")                                                          \
    for (int i = 0; i < 4; ++i) af[i] = *(const s16x8*)(Ab + (arow + i * 16) * 64 + c1); \
    b01[0] = *(const s16x8*)(Bb + (brow +  0) * 64 + c1);                      \
    b01[1] = *(const s16x8*)(Bb + (brow + 16) * 64 + c1);                      \
    if (pre) { stageB(kt + 2, nbufe, 2); stageB(kt + 2, nbufe, 3); }           \
    asm volatile("s_waitcnt lgkmcnt(0)" ::: "memory");                         \
    __builtin_amdgcn_sched_barrier(0);                                         \
    __builtin_amdgcn_s_setprio(1);                                             \
    _Pragma("unroll")                                                          \
    for (int i = 0; i < 4; ++i) {                                              \
      acc[i][0] = __builtin_amdgcn_mfma_f32_16x16x32_bf16(af[i], b01[0], acc[i][0], 0, 0, 0); \
      acc[i][1] = __builtin_amdgcn_mfma_f32_16x16x32_bf16(af[i], b01[1], acc[i][1], 0, 0, 0); \
    }                                                                          \
    __builtin_amdgcn_s_setprio(0);                                             \
    b23[0] = *(const s16x8*)(Bb + (brow + 64) * 64 + c1);                      \
    b23[1] = *(const s16x8*)(Bb + (brow + 80) * 64 + c1);                      \
    asm volatile("s_waitcnt lgkmcnt(0)" ::: "memory");                         \
    __builtin_amdgcn_sched_barrier(0);                                         \
    __builtin_amdgcn_s_setprio(1);                                             \
    _Pragma("unroll")                                                          \
    for (int i = 0; i < 4; ++i) {                                              \
      acc[i][2] = __builtin_amdgcn_mfma_f32_16x16x32_bf16(af[i], b23[0], acc[i][2], 0, 0, 0); \
      acc[i][3] = __builtin_amdgcn_mfma_f32_16x16x32_bf16(af[i], b23[1], acc[i][3], 0, 0, 0); \
    }                                                                          \
    __builtin_amdgcn_s_setprio(0);                                             \
    bi = (bi + 1 == 3) ? 0 : bi + 1;                                           \
  }

// generic single-tensor GEMM (MODE 0 = fp32 row-major; used for out-proj)
template<int MODE>
__global__ __launch_bounds__(512)
void gemm_bt(const unsigned short* __restrict__ A, const unsigned short* __restrict__ B,
             float* __restrict__ Cf, unsigned short* __restrict__ Cb,
             int M, int N, int K, int RH, int RO, const float2* __restrict__ cs2,
             float qsc) {
  __shared__ unsigned short lds[3 * BUFE];   // 144 KiB
  const int tid = threadIdx.x;
  const int lane = tid & 63;
  const int wave = tid >> 6;
  const int lo = lane & 15, hi = lane >> 4;
  const int wm = wave >> 2, wn = wave & 3;

  const int nwg = gridDim.x * gridDim.y;
  const int orig = blockIdx.y * gridDim.x + blockIdx.x;
  const int wg = (orig & 7) * (nwg >> 3) + (orig >> 3);
  const int bx = wg % gridDim.x, by = wg / gridDim.x;
  const int m0 = by * 128, n0 = bx * 256;

  auto stageA = [&](int kt, int bufe, int g) {
    int j0 = g * 512 + wave * 64;
    int j = j0 + lane;
    int row = j >> 3, cb = j & 7;
    gload_lds16(A + (size_t)(m0 + row) * K + kt * GBK + ((cb ^ (row & 7)) << 3),
                (void*)(lds + bufe + j0 * 8));
  };
  auto stageB = [&](int kt, int bufe, int g) {
    int j0 = g * 512 + wave * 64;
    int j = j0 + lane;
    int row = j >> 3, cb = j & 7;
    gload_lds16(B + (size_t)(n0 + row) * K + kt * GBK + ((cb ^ (row & 7)) << 3),
                (void*)(lds + bufe + ABUF + j0 * 8));
  };

  GEMM_MAIN_LOOP

#pragma unroll
  for (int i = 0; i < 4; ++i) {
#pragma unroll
    for (int j = 0; j < 4; ++j) {
#pragma unroll
      for (int r = 0; r < 4; ++r) {
        int row = m0 + wm * 64 + i * 16 + hi * 4 + r;   // C/D: row=(l>>4)*4+reg
        int col = n0 + bbase + (j >> 1) * 64 + (j & 1) * 16 + lo;
        float v = acc[i][j][r];
        if (MODE == 0) {
          Cf[(size_t)row * N + col] = v;
        } else {
          int hh = col >> 7, d = col & 127;
          Cb[((size_t)hh * RH + RO + row) * HD + d] = f2bf(v);
        }
      }
    }
  }
}

// Merged Q+K+V projection: 768 blocks; after bijective XCD swizzle,
// grp = wg/256 selects {Q: RoPE+SC2 -> qbf, K: RoPE -> kallp, V: transposed
// -> vallT}. Body identical to gemm_bt; epilogue branches are wave-uniform.
__global__ __launch_bounds__(512)
void gemm_qkv(const unsigned short* __restrict__ A,
              const unsigned short* __restrict__ B0, const unsigned short* __restrict__ B1,
              const unsigned short* __restrict__ B2,
              unsigned short* __restrict__ C0, unsigned short* __restrict__ C1,
              unsigned short* __restrict__ C2,
              const float2* __restrict__ cs2) {
  __shared__ unsigned short lds[3 * BUFE];   // 144 KiB
  const int tid = threadIdx.x;
  const int lane = tid & 63;
  const int wave = tid >> 6;
  const int lo = lane & 15, hi = lane >> 4;
  const int wm = wave >> 2, wn = wave & 3;

  const int nwg = gridDim.x * gridDim.y;                 // 768
  const int orig = blockIdx.y * gridDim.x + blockIdx.x;
  const int wg = (orig & 7) * (nwg >> 3) + (orig >> 3);
  const int grp = wg >> 8;                               // 0=Q 1=K 2=V
  const int rem = wg & 255;
  const int bx = rem & 15, by = rem >> 4;
  const int m0 = by * 128, n0 = bx * 256;

  const unsigned short* B = (grp == 0) ? B0 : (grp == 1) ? B1 : B2;
  const int K = HID;

  auto stageA = [&](int kt, int bufe, int g) {
    int j0 = g * 512 + wave * 64;
    int j = j0 + lane;
    int row = j >> 3, cb = j & 7;
    gload_lds16(A + (size_t)(m0 + row) * K + kt * GBK + ((cb ^ (row & 7)) << 3),
                (void*)(lds + bufe + j0 * 8));
  };
  auto stageB = [&](int kt, int bufe, int g) {
    int j0 = g * 512 + wave * 64;
    int j = j0 + lane;
    int row = j >> 3, cb = j & 7;
    gload_lds16(B + (size_t)(n0 + row) * K + kt * GBK + ((cb ^ (row & 7)) << 3),
                (void*)(lds + bufe + ABUF + j0 * 8));
  };

  GEMM_MAIN_LOOP

  if (grp < 2) {
    // RoPE epilogue (Q: qsc=SC2, dst qbf/QLEN/0; K: qsc=1, dst kallp/KVLEN/NTOPK)
    unsigned short* Cb = grp ? C1 : C0;
    const float qsc = grp ? 1.0f : (float)SC2;
    const int RH = grp ? KVLEN : QLEN;
    const int RO = grp ? NTOPK : 0;
#pragma unroll
    for (int i = 0; i < 4; ++i) {
#pragma unroll
      for (int j = 0; j < 2; ++j) {
#pragma unroll
        for (int r = 0; r < 4; ++r) {
          int row = m0 + wm * 64 + i * 16 + hi * 4 + r;
          int col = n0 + bbase + j * 16 + lo;
          int hh = col >> 7, d = col & 127;          // d in [0,64)
          float2 cp = cs2[row * 64 + d];
          float x1 = acc[i][j][r] * qsc, x2 = acc[i][j + 2][r] * qsc;
          size_t base = ((size_t)hh * RH + RO + row) * HD;
          Cb[base + d]      = f2bf(x1 * cp.x - x2 * cp.y);
          Cb[base + d + 64] = f2bf(x2 * cp.x + x1 * cp.y);
        }
      }
    }
  } else {
    // V: transposed store vallT[h][d][NTOPK + kv], 4 consecutive kv per reg quad
#pragma unroll
    for (int i = 0; i < 4; ++i) {
#pragma unroll
      for (int j = 0; j < 4; ++j) {
        int rowb = m0 + wm * 64 + i * 16 + hi * 4;
        int col = n0 + bbase + (j >> 1) * 64 + (j & 1) * 16 + lo;
        int hh = col >> 7, d = col & 127;
        u16x4 o4;
#pragma unroll
        for (int r = 0; r < 4; ++r) o4[r] = f2bf(acc[i][j][r]);
        *(u16x4*)(C2 + ((size_t)hh * HD + d) * KVLEN + NTOPK + rowb) = o4;
      }
    }
  }
}

// ---------------- flash attention ----------------
// R17: block = (head, 128-row q-chunk), 8 waves x 16 rows. Each staged K/V
// tile feeds 2x the compute of the R7 layout (per-head tile-stagings drop
// 592 -> 304) with IDENTICAL per-wave register state (o[8], ~96 VGPR; this
// is NOT R8's 32-rows/wave which blew registers). 512 blocks = 2/CU x 8
// waves = 16 waves/CU (vs R7's 12). LDS 50.4KB. Serial single-buffer
// staging (proven). Per-wave diagonal skip (kt > diagkt); causal mask only
// for kt >= nt-2 (derived: tile nt-3 max kv-NTOPK = 128c-1 < all rows).
__global__ __launch_bounds__(512)
void attn_kernel(const unsigned short* __restrict__ qh,
                 const unsigned short* __restrict__ kall,
                 const unsigned short* __restrict__ vallT,
                 const float* __restrict__ sshift,
                 unsigned short* __restrict__ ctx) {
  __shared__ __align__(1024) unsigned short Ks[64 * 128];
  __shared__ __align__(1024) unsigned short Vs[128 * 64];
  __shared__ __align__(16)  unsigned short Plds[8][16 * 72];

  int orig = blockIdx.y * 16 + blockIdx.x;     // 0..511
  int wgid = (orig & 7) * 64 + (orig >> 3);    // bijective XCD swizzle (512 = 8*64)
  int h = wgid >> 4;                           // 4 heads per XCD chunk
  int qc = 15 - (wgid & 15);                   // heaviest chunks launch first

  const int tid = threadIdx.x;
  const int lane = tid & 63;
  const int wave = tid >> 6;                   // 0..7
  const int lo = lane & 15;
  const int hi = lane >> 4;
  const float shiftL = sshift[h] * LOG2E;

  const unsigned short* kb = kall + (size_t)h * KVLEN * HD;
  const unsigned short* vtb = vallT + (size_t)h * HD * KVLEN;

  const int m0 = qc * 128;
  const int nt = 2 * qc + 4;
  const int qrow = m0 + wave * 16 + hi * 4;
  const int diagkt = (m0 + wave * 16 + 15 + NTOPK) >> 6;   // last visible tile

  s16x8 qf[4];
  {
    const unsigned short* qp = qh + ((size_t)h * QLEN + m0 + wave * 16 + lo) * HD + hi * 8;
#pragma unroll
    for (int kc = 0; kc < 4; ++kc) qf[kc] = *(const s16x8*)(qp + kc * 32);
  }

  float m_run[4], l_part[4];
#pragma unroll
  for (int r = 0; r < 4; ++r) { m_run[r] = -1e30f; l_part[r] = 0.f; }
  f32x4 o[8] = {};

  for (int kt = 0; kt < nt; ++kt) {
    const unsigned short* kg = kb + (size_t)kt * 64 * HD;
    const unsigned short* vg = vtb + kt * 64;
    __syncthreads();   // prior tile's readers done before overwrite
#pragma unroll
    for (int it = 0; it < 2; ++it) {
      int j0 = it * 512 + wave * 64;
      int j = j0 + lane;
      int row = j >> 4, cb = j & 15;
      gload_lds16(kg + row * 128 + ((cb ^ (row & 7)) * 8), (void*)(Ks + j0 * 8));
      int d = j >> 3, c8 = j & 7;
      gload_lds16(vg + (size_t)d * KVLEN + ((c8 ^ (d & 7)) << 3), (void*)(Vs + j0 * 8));
    }
    __syncthreads();   // implicit vmcnt(0): tile staged & visible

    if (kt <= diagkt) {
      // S = Q K^T : 16 q-rows x 64 keys per wave (Q pre-scaled by SC2)
      f32x4 s[4] = {};
#pragma unroll
      for (int kc = 0; kc < 4; ++kc) {
#pragma unroll
        for (int g = 0; g < 4; ++g) {
          int key = g * 16 + lo;
          s16x8 kf = *(const s16x8*)(Ks + key * 128 + (((kc * 4 + hi) ^ (key & 7)) * 8));
          s[g] = __builtin_amdgcn_mfma_f32_16x16x32_bf16(qf[kc], kf, s[g], 0, 0, 0);
        }
      }

      // tile-type adjustment (uniform branches)
      if (kt < 2) {
#pragma unroll
        for (int g = 0; g < 4; ++g)
#pragma unroll
          for (int r = 0; r < 4; ++r) s[g][r] += shiftL;
      } else if (kt >= nt - 2) {
        const int kvbase = kt * 64;
#pragma unroll
        for (int r = 0; r < 4; ++r) {
          int qr = qrow + r;
#pragma unroll
          for (int g = 0; g < 4; ++g) {
            int kv = kvbase + g * 16 + lo;
            s[g][r] = (kv - NTOPK > qr) ? PADV : s[g][r];
          }
        }
      }

      // vote-based defer-max
      float mx[4];
      bool need = false;
#pragma unroll
      for (int r = 0; r < 4; ++r) {
        mx[r] = fmaxf(fmaxf(s[0][r], s[1][r]), fmaxf(s[2][r], s[3][r]));
        need = need || (mx[r] > m_run[r] + DEFER_THR);
      }
      if (__any((int)need)) {
#pragma unroll
        for (int off = 1; off < 16; off <<= 1)
#pragma unroll
          for (int r = 0; r < 4; ++r) mx[r] = fmaxf(mx[r], __shfl_xor(mx[r], off, 64));
#pragma unroll
        for (int r = 0; r < 4; ++r) {
          float mn = fmaxf(m_run[r], mx[r]);
          float alpha = __builtin_amdgcn_exp2f(m_run[r] - mn);
          m_run[r] = mn;
          l_part[r] *= alpha;
#pragma unroll
          for (int db = 0; db < 8; ++db) o[db][r] *= alpha;
        }
      }

      // p = exp2(s - m), lane-partial l, P -> LDS
#pragma unroll
      for (int r = 0; r < 4; ++r) {
#pragma unroll
        for (int g = 0; g < 4; ++g) {
          float p = __builtin_amdgcn_exp2f(s[g][r] - m_run[r]);
          l_part[r] += p;
          Plds[wave][(hi * 4 + r) * 72 + g * 16 + lo] = f2bf(p);
        }
      }

      // PV: A = P (same-wave LDS round trip), B = V^T single b128 per frag
      s16x8 pf0 = *(const s16x8*)(&Plds[wave][lo * 72 + hi * 8]);
      s16x8 pf1 = *(const s16x8*)(&Plds[wave][lo * 72 + 32 + hi * 8]);
#pragma unroll
      for (int db = 0; db < 8; ++db) {
        int d = db * 16 + lo;
        s16x8 vf0 = *(const s16x8*)(Vs + d * 64 + ((hi       ^ (d & 7)) << 3));
        s16x8 vf1 = *(const s16x8*)(Vs + d * 64 + (((4 + hi) ^ (d & 7)) << 3));
        o[db] = __builtin_amdgcn_mfma_f32_16x16x32_bf16(pf0, vf0, o[db], 0, 0, 0);
        o[db] = __builtin_amdgcn_mfma_f32_16x16x32_bf16(pf1, vf1, o[db], 0, 0, 0);
      }
    } // kt <= diagkt
  } // kt

  // reduce lane-partial l across the 16 lo lanes (once per block)
#pragma unroll
  for (int off = 1; off < 16; off <<= 1)
#pragma unroll
    for (int r = 0; r < 4; ++r) l_part[r] += __shfl_xor(l_part[r], off, 64);

  float rinv[4];
#pragma unroll
  for (int r = 0; r < 4; ++r) rinv[r] = __builtin_amdgcn_rcpf(l_part[r]);

  // normalize + write ctx[q][h*128+d] bf16
#pragma unroll
  for (int db = 0; db < 8; ++db) {
#pragma unroll
    for (int r = 0; r < 4; ++r) {
      int row = qrow + r;
      int col = h * HD + db * 16 + lo;
      ctx[(size_t)row * HID + col] = f2bf(o[db][r] * rinv[r]);
    }
  }
}

// ---------------- launch ----------------

extern "C" void kernel_launch(void* const* d_in, const int* in_sizes, int n_in,
                              void* d_out, int out_size, void* d_ws, size_t ws_size,
                              hipStream_t stream) {
  const float* hidden    = (const float*)d_in[0];
  const int*   pos       = (const int*)d_in[2];
  const float* kb_keys   = (const float*)d_in[3];
  const float* kb_values = (const float*)d_in[4];
  const float* Wq        = (const float*)d_in[5];
  const float* Wq2       = (const float*)d_in[6];
  const float* Wk        = (const float*)d_in[7];
  const float* Wv        = (const float*)d_in[8];
  const float* Wo        = (const float*)d_in[9];
  const float* sshift    = (const float*)d_in[10];
  float* out = (float*)d_out;

  char* ws = (char*)d_ws;
  size_t off = 0;
  auto alloc = [&](size_t bytes) { char* p = ws + off; off += (bytes + 255) & ~(size_t)255; return p; };
  unsigned short* hidden_bf = (unsigned short*)alloc((size_t)QLEN * HID * 2);
  unsigned short* wbuf      = (unsigned short*)alloc((size_t)HID * HID * 2);   // Wq bf16
  unsigned short* wvbuf     = (unsigned short*)alloc((size_t)HID * HID * 2);   // Wv bf16
  unsigned short* wobuf     = (unsigned short*)alloc((size_t)HID * HID * 2);   // Wo bf16
  unsigned short* qbf       = (unsigned short*)alloc((size_t)NH * QLEN * HD * 2);
  unsigned short* kallp     = (unsigned short*)alloc((size_t)NH * KVLEN * HD * 2);
  unsigned short* vallT     = (unsigned short*)alloc((size_t)NH * HD * KVLEN * 2);
  unsigned short* ctx       = (unsigned short*)alloc((size_t)QLEN * HID * 2);
  float2*         cs2       = (float2*)alloc((size_t)QLEN * 64 * 8);
  float*          part      = (float*)alloc((size_t)16 * HID * 4);
  float*          hsum      = (float*)alloc(HID * 4);
  float*          qs        = (float*)alloc(HID * 4);
  float*          scores    = (float*)alloc(KBLEN * 4);
  int*            idx       = (int*)alloc(NTOPK * 4);

  // d_out (33.55MB fp32 = exactly HID*HID bf16) is dead until the final
  // out-projection, which overwrites every element -> use as Wk-bf16 scratch.
  unsigned short* wkbuf = (unsigned short*)out;

  dim3 blk(256);
  int wcast_blocks = HID * HID / 4 / 256;

  k_cast<<<QLEN * HID / 4 / 256, blk, 0, stream>>>(hidden, hidden_bf, QLEN * HID / 4);
  k_rowsum_p<<<dim3(HID / 256, 16), blk, 0, stream>>>(hidden, part);
  k_rowsum_r<<<HID / 256, blk, 0, stream>>>(part, hsum);
  k_dotrows<<<HID / 4, blk, 0, stream>>>(hsum, Wq2, qs, HID, 1.0f);
  k_dotrows<<<KBLEN / 4, blk, 0, stream>>>(qs, kb_keys, scores, HID, SCALE);
  k_topk<<<1, KBLEN, 0, stream>>>(scores, idx);
  k_cs<<<QLEN * 64 / 256, blk, 0, stream>>>(pos, cs2);

  // all four weight casts in one launch
  k_cast4<<<4 * wcast_blocks, blk, 0, stream>>>(Wq, Wk, Wv, Wo,
                                                wbuf, wkbuf, wvbuf, wobuf,
                                                HID * HID / 4);

  // merged Q+K+V projection (+RoPE, +V-transpose) -- 768 blocks
  dim3 gblk(512);
  dim3 qkvgrid(16, 48);
  gemm_qkv<<<qkvgrid, gblk, 0, stream>>>(hidden_bf, wbuf, wkbuf, wvbuf,
                                         qbf, kallp, vallT, cs2);

  // gather selected KB keys/values into k_all[:, :128] / v_all^T[:, :, :128]
  k_gather<<<NH * NTOPK * HD / 256, blk, 0, stream>>>(kb_keys, kb_values, idx, kallp, vallT);

  // flash attention -> ctx bf16 [q][h*128+d]  (512 blocks x 8 waves)
  dim3 agrid(16, NH);
  attn_kernel<<<agrid, gblk, 0, stream>>>(qbf, kallp, vallT, sshift, ctx);

  // output projection -> d_out fp32 (overwrites the wkbuf scratch fully)
  dim3 ggrid(HID / 256, QLEN / 128);  // 256 blocks
  gemm_bt<0><<<ggrid, gblk, 0, stream>>>(ctx, wobuf, out, nullptr, QLEN, HID, HID, 0, 0, cs2, 1.0f);
}